// Round 8
// baseline (1071.524 us; speedup 1.0000x reference)
//
#include <hip/hip_runtime.h>
#include <math.h>

// ---- problem constants ----
#define Bb 32
#define DFc 8
#define Hh 144
#define Ww 144
#define OFFc 2
#define KWc 5
#define DSc 512
#define DTc 1024
#define NCc 6
#define HEADSc 16
#define DHc 64
#define MLPc 2048
#define CINc (DFc * Ww)        // 1152
#define ITCc (DFc * Hh * KWc)  // 5760
#define BHc (Bb * Hh)          // 4608
#define INNERc (HEADSc * DHc)  // 1024
#define EPSc 1e-5f
#define THRc 0.3f
#define WLNc 4608              // per-nc worklist capacity (max columns per nc)
#define GAPDELTA 1e-3f

typedef __attribute__((ext_vector_type(8))) short short8;
typedef __attribute__((ext_vector_type(4))) float f32x4;

#define ATOMIC_ADD_F32(p, v) unsafeAtomicAdd((p), (v))

// bf16 split helpers (manual RTN-even)
__device__ inline unsigned short f2bf(float v) {
    unsigned int u = __float_as_uint(v);
    unsigned int r = (u + 0x7FFFu + ((u >> 16) & 1u)) >> 16;
    return (unsigned short)r;
}
__device__ inline float bf2f(unsigned short b) {
    return __uint_as_float(((unsigned int)b) << 16);
}

// ============================================================
// Permute x(B,DF,H,W) -> Bt[n=(b*H+h)][k=(f*W+w)] and split into 2 bf16 planes.
// ============================================================
__global__ void k_split_x(const float* __restrict__ x, unsigned short* __restrict__ p,
                          long planeStride)
{
    int tid = blockIdx.x * 256 + threadIdx.x;  // = n*CIN + k
    if (tid >= BHc * CINc) return;
    int n = tid / CINc, k = tid % CINc;
    int b = n / Hh, h = n % Hh;
    int f = k / Ww, w = k % Ww;
    float v = x[((long)(b * DFc + f) * Hh + h) * Ww + w];
    unsigned short h0 = f2bf(v);
    p[tid] = h0;
    p[planeStride + tid] = f2bf(v - bf2f(h0));
}

// ============================================================
// Tiled transpose: src [nc][512][1152] -> dst [nc][1152][512]
// grid (36, 16, 6), 256 threads (32x8)
// ============================================================
__global__ __launch_bounds__(256) void k_transpose(
    const float* __restrict__ src, float* __restrict__ dst)
{
    __shared__ float t[32][33];
    const int nc = blockIdx.z;
    const int s0 = blockIdx.y * 32;
    const int k0 = blockIdx.x * 32;
    const int lx = threadIdx.x & 31, ly = threadIdx.x >> 5;
    const float* sp = src + ((long)nc * 512 + s0) * 1152 + k0;
#pragma unroll
    for (int i = 0; i < 32; i += 8)
        t[ly + i][lx] = sp[(long)(ly + i) * 1152 + lx];
    __syncthreads();
    float* dp = dst + ((long)nc * 1152 + k0) * 512 + s0;
#pragma unroll
    for (int i = 0; i < 32; i += 8)
        dp[(long)(ly + i) * 512 + lx] = t[lx][ly + i];
}

// ============================================================
// W2s[nc][Mpad][512] = (o < O) ? w2[nc][o][s] * scale[nc*512+s] : 0
// ============================================================
__global__ void k_w2s(const float* __restrict__ w2, const float* __restrict__ scale,
                      float* __restrict__ Ws, int O, int Mpad)
{
    int i = blockIdx.x * 256 + threadIdx.x;
    if (i >= NCc * Mpad * 512) return;
    int s = i & 511;
    int o = (i >> 9) % Mpad;
    int nc = i / (Mpad * 512);
    float v = 0.f;
    if (o < O) v = w2[((long)nc * O + o) * 512 + s] * scale[nc * 512 + s];
    Ws[i] = v;
}

// ============================================================
// Batched plain-store NT GEMM: C[z][m][1152-ld] = A[z][m][K] @ B[z][n][K]^T
// 64x64 tile, BK=16, grid (n/64, m/64, z). Reg-prefetch pipelined.
// ============================================================
__global__ __launch_bounds__(256) void gemm_nt_b(
    const float* __restrict__ A, long sAz,
    const float* __restrict__ Bm, long sBz,
    float* __restrict__ C, long sCz, int K)
{
    __shared__ float As[16][68];
    __shared__ float Bs[16][68];
    const int tid = threadIdx.x;
    const int n0 = blockIdx.x * 64;
    const int m0 = blockIdx.y * 64;
    const int z = blockIdx.z;
    const int lRow = tid >> 2, lCol = (tid & 3) << 2;
    const int ty = tid >> 4, tx = tid & 15;
    const float* Az = A + (long)z * sAz + (long)(m0 + lRow) * K + lCol;
    const float* Bz = Bm + (long)z * sBz + (long)(n0 + lRow) * K + lCol;

    float acc[4][4];
#pragma unroll
    for (int i = 0; i < 4; i++)
#pragma unroll
        for (int j = 0; j < 4; j++) acc[i][j] = 0.f;

    float4 av = *(const float4*)(Az);
    float4 bv = *(const float4*)(Bz);
    for (int k0 = 0; k0 < K; k0 += 16) {
        As[lCol + 0][lRow] = av.x; As[lCol + 1][lRow] = av.y;
        As[lCol + 2][lRow] = av.z; As[lCol + 3][lRow] = av.w;
        Bs[lCol + 0][lRow] = bv.x; Bs[lCol + 1][lRow] = bv.y;
        Bs[lCol + 2][lRow] = bv.z; Bs[lCol + 3][lRow] = bv.w;
        __syncthreads();
        if (k0 + 16 < K) {
            av = *(const float4*)(Az + k0 + 16);
            bv = *(const float4*)(Bz + k0 + 16);
        }
#pragma unroll
        for (int kk = 0; kk < 16; kk++) {
            float4 a = *(const float4*)&As[kk][ty * 4];
            float4 b = *(const float4*)&Bs[kk][tx * 4];
            float aa[4] = {a.x, a.y, a.z, a.w};
            float bb[4] = {b.x, b.y, b.z, b.w};
#pragma unroll
            for (int i = 0; i < 4; i++)
#pragma unroll
                for (int j = 0; j < 4; j++) acc[i][j] += aa[i] * bb[j];
        }
        __syncthreads();
    }
    const int ncol = n0 + tx * 4;
#pragma unroll
    for (int i = 0; i < 4; i++) {
        float* cp = C + (long)z * sCz + (long)(m0 + ty * 4 + i) * 1152 + ncol;
#pragma unroll
        for (int j = 0; j < 4; j++) cp[j] = acc[i][j];
    }
}

// ============================================================
// effB[nc][256]: o<144: b2c + sum_s w2c[o][s]*shiftC; o in {144,145}:
// b2e + sum_s w2e[o-144][s]*shiftE; else 0. 16-lane group per output.
// ============================================================
__global__ __launch_bounds__(256) void k_effb(
    const float* __restrict__ w2c, const float* __restrict__ b2c, const float* __restrict__ shiftC,
    const float* __restrict__ w2e, const float* __restrict__ b2e, const float* __restrict__ shiftE,
    float* __restrict__ effB)
{
    int g = blockIdx.x * 16 + (threadIdx.x >> 4);
    int lane = threadIdx.x & 15;
    if (g >= NCc * 256) return;
    int nc = g >> 8, o = g & 255;
    float d = 0.f;
    if (o < 144) {
        const float* wp = w2c + ((long)nc * 144 + o) * 512;
        const float* sp = shiftC + nc * 512;
        for (int s = lane; s < 512; s += 16) d += wp[s] * sp[s];
    } else if (o < 146) {
        const float* wp = w2e + ((long)nc * 2 + (o - 144)) * 512;
        const float* sp = shiftE + nc * 512;
        for (int s = lane; s < 512; s += 16) d += wp[s] * sp[s];
    }
#pragma unroll
    for (int off = 8; off; off >>= 1) d += __shfl_xor(d, off);
    if (lane == 0) {
        float b = (o < 144) ? b2c[nc * 144 + o] : ((o < 146) ? b2e[nc * 2 + o - 144] : 0.f);
        effB[g] = d + b;
    }
}

// ============================================================
// Split effW fp32 [nc][256][1152] (rows >=208 garbage) into 2 bf16 planes
// ============================================================
__global__ void k_split_effw(const float* __restrict__ effW, unsigned short* __restrict__ p,
                             long planeStride)
{
    int i = blockIdx.x * 256 + threadIdx.x;  // over 6*256*1152 = 1,769,472
    if (i >= NCc * 256 * 1152) return;
    int o = (i / 1152) & 255;
    float v = (o < 208) ? effW[i] : 0.f;
    unsigned short h0 = f2bf(v);
    p[i] = h0;
    p[planeStride + i] = f2bf(v - bf2f(h0));
}

// ============================================================
// Fused head GEMM (MFMA, split-bf16, 3 products): per nc,
// logits[o][col] = effW[nc][o][:] . X[col][:]  (K=1152)
// A = effW planes [nc][256][1152], B = X planes [col][1152].
// grid (36, 2, 6), 128x128 tiles, BK=32, 2-phase dbuf + T2 both-sides swizzle.
// Epilogue: o<144 -> cls lgT[nc][col][o] (float4); o==144 -> ext logits
// extLg[nc][col][2]. Bias effB[nc*256+o].
// ============================================================
__global__ __launch_bounds__(256) void gemm_fused(
    const unsigned short* __restrict__ Ag, long strideA,
    const unsigned short* __restrict__ Bg, long strideB,
    float* __restrict__ lgT, float* __restrict__ extLg,
    const float* __restrict__ effB)
{
    constexpr int K = 1152;
    constexpr int PAt[3] = {0, 0, 1};
    constexpr int PBt[3] = {0, 1, 0};
    __shared__ __align__(16) unsigned short As[2][2][128 * 32];
    __shared__ __align__(16) unsigned short Bs[2][2][128 * 32];
    const int tid = threadIdx.x;
    const int w = tid >> 6;
    const int l = tid & 63;
    const int quad = l >> 4, l15 = l & 15;
    const int z = blockIdx.z;
    const int m0 = blockIdx.y * 128, n0 = blockIdx.x * 128;
    const int rw = (w >> 1) * 64, cw = (w & 1) * 64;

    f32x4 acc[4][4];
#pragma unroll
    for (int i = 0; i < 4; i++)
#pragma unroll
        for (int j = 0; j < 4; j++) acc[i][j] = (f32x4){0.f, 0.f, 0.f, 0.f};

    const int srow = w * 32;
    const int lr = l >> 2;
    const int lc = ((l & 3) ^ ((lr >> 1) & 3)) * 8;  // pre-swizzled source slot
    const unsigned short* gA[2];
    const unsigned short* gB[2];
#pragma unroll
    for (int p = 0; p < 2; p++) {
        gA[p] = Ag + (long)p * strideA + ((long)(z * 256 + m0 + srow + lr)) * K + lc;
        gB[p] = Bg + (long)p * strideB + ((long)(n0 + srow + lr)) * K + lc;
    }
    const int ldsOff0 = srow * 32;
    const int ldsOff1 = (srow + 16) * 32;
    const int rdoff = (quad ^ ((l15 >> 1) & 3)) * 8;  // swizzled read slot

    auto STAGE = [&](int buf, int k0) {
#pragma unroll
        for (int p = 0; p < 2; p++) {
            __builtin_amdgcn_global_load_lds(
                (const __attribute__((address_space(1))) void*)(gA[p] + k0),
                (__attribute__((address_space(3))) void*)&As[buf][p][ldsOff0], 16, 0, 0);
            __builtin_amdgcn_global_load_lds(
                (const __attribute__((address_space(1))) void*)(gA[p] + 16 * K + k0),
                (__attribute__((address_space(3))) void*)&As[buf][p][ldsOff1], 16, 0, 0);
            __builtin_amdgcn_global_load_lds(
                (const __attribute__((address_space(1))) void*)(gB[p] + k0),
                (__attribute__((address_space(3))) void*)&Bs[buf][p][ldsOff0], 16, 0, 0);
            __builtin_amdgcn_global_load_lds(
                (const __attribute__((address_space(1))) void*)(gB[p] + 16 * K + k0),
                (__attribute__((address_space(3))) void*)&Bs[buf][p][ldsOff1], 16, 0, 0);
        }
    };

    const int nk = K >> 5;  // 36
    STAGE(0, 0);
    __syncthreads();
    int cur = 0;
    for (int t = 0; t < nk; ++t) {
        if (t + 1 < nk) STAGE(cur ^ 1, (t + 1) << 5);

        short8 af[2][4], bf[2][4];
#pragma unroll
        for (int p = 0; p < 2; p++)
#pragma unroll
            for (int i = 0; i < 4; i++) {
                af[p][i] = *(const short8*)&As[cur][p][(rw + i * 16 + l15) * 32 + rdoff];
                bf[p][i] = *(const short8*)&Bs[cur][p][(cw + i * 16 + l15) * 32 + rdoff];
            }
#pragma unroll
        for (int t2 = 0; t2 < 3; t2++) {
            const int pa = PAt[t2], pb = PBt[t2];
#pragma unroll
            for (int i = 0; i < 4; i++)
#pragma unroll
                for (int j = 0; j < 4; j++)
                    acc[i][j] = __builtin_amdgcn_mfma_f32_16x16x32_bf16(
                        af[pa][i], bf[pb][j], acc[i][j], 0, 0, 0);
        }
        __syncthreads();
        cur ^= 1;
    }

#pragma unroll
    for (int i = 0; i < 4; i++) {
        int ob = m0 + rw + i * 16 + quad * 4;
        if (ob < 144) {
            float4 bb = *(const float4*)(effB + z * 256 + ob);
#pragma unroll
            for (int j = 0; j < 4; j++) {
                int col = n0 + cw + j * 16 + l15;
                float4 v = make_float4(acc[i][j][0] + bb.x, acc[i][j][1] + bb.y,
                                       acc[i][j][2] + bb.z, acc[i][j][3] + bb.w);
                *(float4*)(lgT + ((long)(z * BHc + col)) * 144 + ob) = v;
            }
        } else if (ob == 144) {
            float b0 = effB[z * 256 + 144];
            float b1 = effB[z * 256 + 145];
#pragma unroll
            for (int j = 0; j < 4; j++) {
                int col = n0 + cw + j * 16 + l15;
                float* ep = extLg + ((long)z * BHc + col) * 2;
                ep[0] = acc[i][j][0] + b0;
                ep[1] = acc[i][j][1] + b1;
            }
        }
    }
}

// ============================================================
// Bias init: mode 0: C[m][n] = bias[n] (or 0); mode 1: C[m][n] += bias[n]
// ============================================================
__global__ void k_bias(float* __restrict__ C, const float* __restrict__ bias,
                       int M, int N, int add)
{
    int idx = blockIdx.x * 256 + threadIdx.x;
    if (idx >= M * N) return;
    int n = idx % N;
    float v = bias ? bias[n] : 0.f;
    C[idx] = add ? C[idx] + v : v;
}

// tok init: tok[row][n] = tok_b[n] + emb[row%NC][n]
__global__ void k_tok_init(float* __restrict__ tok, const float* __restrict__ tok_b,
                           const float* __restrict__ emb)
{
    int tid = blockIdx.x * 256 + threadIdx.x;
    if (tid >= Bb * NCc * DTc) return;
    int row = tid >> 10, n = tid & 1023;
    tok[tid] = tok_b[n] + emb[(row % NCc) * DTc + n];
}

// ============================================================
// Split-K NT GEMM: C += A[MxK] @ B[NxK]^T over k-chunk blockIdx.z.
// Reg-prefetch pipelined; fp32 atomic-add epilogue. C pre-initialized.
// NOTE: kc MUST be a multiple of 16 (BK) — non-multiple overlaps chunks.
// ============================================================
__global__ __launch_bounds__(256) void gemm_nt_sk(
    const float* __restrict__ A, const float* __restrict__ Bm, float* __restrict__ C,
    int M, int N, int K, int kc)
{
    __shared__ float As[16][68];
    __shared__ float Bs[16][68];
    const int tid = threadIdx.x;
    const int n0 = blockIdx.x * 64;
    const int m0 = blockIdx.y * 64;
    const int ks = blockIdx.z * kc;
    const int ke = min(K, ks + kc);
    const int lRow = tid >> 2, lCol = (tid & 3) << 2;
    const int ty = tid >> 4, tx = tid & 15;
    const float* Ap = A + (long)(m0 + lRow) * K + lCol;
    const float* Bp = Bm + (long)(n0 + lRow) * K + lCol;

    float acc[4][4];
#pragma unroll
    for (int i = 0; i < 4; i++)
#pragma unroll
        for (int j = 0; j < 4; j++) acc[i][j] = 0.f;

    float4 av = *(const float4*)(Ap + ks);
    float4 bv = *(const float4*)(Bp + ks);
    for (int k0 = ks; k0 < ke; k0 += 16) {
        As[lCol + 0][lRow] = av.x; As[lCol + 1][lRow] = av.y;
        As[lCol + 2][lRow] = av.z; As[lCol + 3][lRow] = av.w;
        Bs[lCol + 0][lRow] = bv.x; Bs[lCol + 1][lRow] = bv.y;
        Bs[lCol + 2][lRow] = bv.z; Bs[lCol + 3][lRow] = bv.w;
        __syncthreads();
        if (k0 + 16 < ke) {
            av = *(const float4*)(Ap + k0 + 16);
            bv = *(const float4*)(Bp + k0 + 16);
        }
#pragma unroll
        for (int kk = 0; kk < 16; kk++) {
            float4 a = *(const float4*)&As[kk][ty * 4];
            float4 b = *(const float4*)&Bs[kk][tx * 4];
            float aa[4] = {a.x, a.y, a.z, a.w};
            float bb[4] = {b.x, b.y, b.z, b.w};
#pragma unroll
            for (int i = 0; i < 4; i++)
#pragma unroll
                for (int j = 0; j < 4; j++) acc[i][j] += aa[i] * bb[j];
        }
        __syncthreads();
    }
    const int ncol = n0 + tx * 4;
#pragma unroll
    for (int i = 0; i < 4; i++) {
        int row = m0 + ty * 4 + i;
        float* cp = C + (long)row * N + ncol;
#pragma unroll
        for (int j = 0; j < 4; j++) ATOMIC_ADD_F32(cp + j, acc[i][j]);
    }
}

// ============================================================
// Full-K NT GEMM, plain store + bias: C[m][n] = A@B^T + bias[n].
// 64x64 tile, BK=16, reg-prefetch pipelined. grid (N/64, M/64).
// ============================================================
__global__ __launch_bounds__(256) void gemm_nt_f(
    const float* __restrict__ A, const float* __restrict__ Bm, float* __restrict__ C,
    const float* __restrict__ bias, int M, int N, int K)
{
    __shared__ float As[16][68];
    __shared__ float Bs[16][68];
    const int tid = threadIdx.x;
    const int n0 = blockIdx.x * 64;
    const int m0 = blockIdx.y * 64;
    const int lRow = tid >> 2, lCol = (tid & 3) << 2;
    const int ty = tid >> 4, tx = tid & 15;
    const float* Ap = A + (long)(m0 + lRow) * K + lCol;
    const float* Bp = Bm + (long)(n0 + lRow) * K + lCol;

    float acc[4][4];
#pragma unroll
    for (int i = 0; i < 4; i++)
#pragma unroll
        for (int j = 0; j < 4; j++) acc[i][j] = 0.f;

    float4 av = *(const float4*)(Ap);
    float4 bv = *(const float4*)(Bp);
    for (int k0 = 0; k0 < K; k0 += 16) {
        As[lCol + 0][lRow] = av.x; As[lCol + 1][lRow] = av.y;
        As[lCol + 2][lRow] = av.z; As[lCol + 3][lRow] = av.w;
        Bs[lCol + 0][lRow] = bv.x; Bs[lCol + 1][lRow] = bv.y;
        Bs[lCol + 2][lRow] = bv.z; Bs[lCol + 3][lRow] = bv.w;
        __syncthreads();
        if (k0 + 16 < K) {
            av = *(const float4*)(Ap + k0 + 16);
            bv = *(const float4*)(Bp + k0 + 16);
        }
#pragma unroll
        for (int kk = 0; kk < 16; kk++) {
            float4 a = *(const float4*)&As[kk][ty * 4];
            float4 b = *(const float4*)&Bs[kk][tx * 4];
            float aa[4] = {a.x, a.y, a.z, a.w};
            float bb[4] = {b.x, b.y, b.z, b.w};
#pragma unroll
            for (int i = 0; i < 4; i++)
#pragma unroll
                for (int j = 0; j < 4; j++) acc[i][j] += aa[i] * bb[j];
        }
        __syncthreads();
    }
    const int ncol = n0 + tx * 4;
    float4 bb4 = *(const float4*)(bias + ncol);
#pragma unroll
    for (int i = 0; i < 4; i++) {
        int row = m0 + ty * 4 + i;
        float* cp = C + (long)row * N + ncol;
        cp[0] = acc[i][0] + bb4.x;
        cp[1] = acc[i][1] + bb4.y;
        cp[2] = acc[i][2] + bb4.z;
        cp[3] = acc[i][3] + bb4.w;
    }
}

// scale = g*rsqrt(vr+eps); shift = (b1-mu)*scale + bt; optionally zero worklist cnts
__global__ void k_scale_shift(const float* __restrict__ g, const float* __restrict__ vr,
                              const float* __restrict__ mu, const float* __restrict__ bt,
                              const float* __restrict__ b1,
                              float* __restrict__ scale, float* __restrict__ shift, int n,
                              int* __restrict__ wlc)
{
    int i = blockIdx.x * 256 + threadIdx.x;
    if (wlc && i < 8) wlc[i] = 0;
    if (i >= n) return;
    float sc = g[i] * rsqrtf(vr[i] + EPSc);
    scale[i] = sc;
    shift[i] = (b1[i] - mu[i]) * sc + bt[i];
}

// ext head from precomputed logits: softmax (O=2) + exist reduction
__global__ __launch_bounds__(256) void k_ext_head2(
    const float* __restrict__ extLg, float* __restrict__ outExt, int* __restrict__ exist)
{
    __shared__ float red[256];
    const int bc = blockIdx.x;
    const int b = bc / NCc, nc = bc % NCc;
    const int h = threadIdx.x;
    float p0 = 0.f;
    if (h < Hh) {
        const int col = b * Hh + h;
        const float* ep = extLg + ((long)nc * BHc + col) * 2;
        float lg0 = ep[0], lg1 = ep[1];
        float mx = fmaxf(lg0, lg1);
        float e0 = expf(lg0 - mx), e1 = expf(lg1 - mx);
        float inv = 1.f / (e0 + e1);
        p0 = e0 * inv;
        float* op = outExt + ((long)bc * Hh + h) * 2;
        op[0] = p0;
        op[1] = e1 * inv;
    }
    red[threadIdx.x] = p0;
    __syncthreads();
    for (int st = 128; st > 0; st >>= 1) {
        if (threadIdx.x < st) red[threadIdx.x] += red[threadIdx.x + st];
        __syncthreads();
    }
    if (threadIdx.x == 0) exist[bc] = (red[0] / Hh > THRc) ? 1 : 0;
}

// ============================================================
// wave-per-column softmax over lgT[nc][col][144]; top-2 gap flagging (stage1),
// bucketed per-nc worklist: wlc[nc] count, wl[nc*WLN + ix] = col.
// ============================================================
__global__ __launch_bounds__(256) void k_softmax2(
    const float* __restrict__ lgT, float* __restrict__ outCls, int* __restrict__ corr,
    int* __restrict__ wlc, int* __restrict__ wl, int stage1)
{
    int wg = blockIdx.x * 4 + (threadIdx.x >> 6);
    int l = threadIdx.x & 63;
    int nc = wg / BHc, col = wg % BHc;
    int b = col / Hh, h = col % Hh;
    const float* p = lgT + ((long)nc * BHc + col) * 144;
    float v0 = p[l];
    float v1 = p[l + 64];
    float v2 = (l < 16) ? p[l + 128] : -1e30f;
    // per-lane top2 (lower idx wins ties)
    float m1 = v0, m2; int i1 = l;
    if (v1 > m1) { m2 = m1; m1 = v1; i1 = l + 64; } else m2 = v1;
    if (v2 > m1) { m2 = m1; m1 = v2; i1 = l + 128; } else m2 = fmaxf(m2, v2);
    // butterfly top2 merge across 64 lanes
#pragma unroll
    for (int off = 32; off; off >>= 1) {
        float o1 = __shfl_xor(m1, off);
        float o2 = __shfl_xor(m2, off);
        int oi = __shfl_xor(i1, off);
        if (o1 > m1 || (o1 == m1 && oi < i1)) { m2 = fmaxf(m1, o2); m1 = o1; i1 = oi; }
        else m2 = fmaxf(m2, o1);
    }
    float e0 = expf(v0 - m1);
    float e1 = expf(v1 - m1);
    float e2 = (l < 16) ? expf(v2 - m1) : 0.f;
    float s = e0 + e1 + e2;
#pragma unroll
    for (int off = 32; off; off >>= 1) s += __shfl_xor(s, off);
    float inv = 1.f / s;
    int row = (b * NCc + nc) * Hh + h;
    float* op = outCls + (long)row * 144;
    op[l] = e0 * inv;
    op[l + 64] = e1 * inv;
    if (l < 16) op[l + 128] = e2 * inv;
    if (l == 0) {
        corr[row] = i1;
        if (stage1 && (m1 - m2) < GAPDELTA) {
            int ix = atomicAdd(&wlc[nc], 1);
            if (ix < WLNc) wl[nc * WLNc + ix] = col;
        }
    }
}

// ============================================================
// fixup phase A: exact fp32 h for flagged items.
// ============================================================
__global__ __launch_bounds__(256) void k_fixup_h(
    const float* __restrict__ x, const float* __restrict__ w1,
    const float* __restrict__ scale, const float* __restrict__ shift,
    const int* __restrict__ wlc, const int* __restrict__ wl,
    float* __restrict__ hsfix)
{
    const int nc = blockIdx.y;
    const int cnt = min(wlc[nc], WLNc);
    const int chunk = blockIdx.z;  // 0..7
    if (chunk >= cnt) return;
    const int t = threadIdx.x;
    const int r = t >> 4;          // 0..15
    const int lane16 = t & 15;
    const int s = blockIdx.x * 16 + r;  // 0..511
    const float* wp = w1 + ((long)(nc * 512 + s)) * CINc + lane16 * 4;
    float4 wr[18];
#pragma unroll
    for (int i = 0; i < 18; i++) wr[i] = *(const float4*)(wp + 64 * i);
    const float sc = scale[nc * 512 + s];
    const float sh = shift[nc * 512 + s];
    int xoff[18];
#pragma unroll
    for (int i = 0; i < 18; i++) {
        int k = lane16 * 4 + 64 * i;
        xoff[i] = (k / Ww) * (Hh * Ww) + (k % Ww);
    }
    for (int it = chunk; it < cnt; it += 8) {
        int col = wl[nc * WLNc + it];
        int b = col / Hh, h = col % Hh;
        const float* xb = x + (long)b * (DFc * Hh * Ww) + h * Ww;
        float d = 0.f;
#pragma unroll
        for (int i = 0; i < 18; i++) {
            float4 xv = *(const float4*)(xb + xoff[i]);
            d += wr[i].x * xv.x + wr[i].y * xv.y + wr[i].z * xv.z + wr[i].w * xv.w;
        }
#pragma unroll
        for (int off = 8; off; off >>= 1) d += __shfl_xor(d, off);
        if (lane16 == 0) hsfix[((long)nc * WLNc + it) * 512 + s] = d * sc + sh;
    }
}

// ============================================================
// fixup phase B: exact logits lgfix[nc][item][144] = w2 @ hsfix + b2.
// ============================================================
__global__ __launch_bounds__(256) void k_fixup_lg(
    const float* __restrict__ hsfix, const float* __restrict__ w2,
    const float* __restrict__ b2,
    const int* __restrict__ wlc, const int* __restrict__ wl,
    float* __restrict__ lgfix)
{
    const int nc = blockIdx.y;
    const int cnt = min(wlc[nc], WLNc);
    const int chunk = blockIdx.z;
    if (chunk >= cnt) return;
    const int t = threadIdx.x;
    const int r = t >> 4;
    const int lane16 = t & 15;
    const int o = blockIdx.x * 16 + r;  // 0..143
    const float* wp = w2 + ((long)(nc * 144 + o)) * 512 + lane16 * 4;
    float4 wr[8];
#pragma unroll
    for (int i = 0; i < 8; i++) wr[i] = *(const float4*)(wp + 64 * i);
    const float bb = b2[nc * 144 + o];
    for (int it = chunk; it < cnt; it += 8) {
        const float* hp = hsfix + ((long)nc * WLNc + it) * 512 + lane16 * 4;
        float d = 0.f;
#pragma unroll
        for (int i = 0; i < 8; i++) {
            float4 hv = *(const float4*)(hp + 64 * i);
            d += wr[i].x * hv.x + wr[i].y * hv.y + wr[i].z * hv.z + wr[i].w * hv.w;
        }
#pragma unroll
        for (int off = 8; off; off >>= 1) d += __shfl_xor(d, off);
        if (lane16 == 0) lgfix[((long)nc * WLNc + it) * 144 + o] = d + bb;
    }
}

// ============================================================
// fixup phase C: per flagged item (one wave each): exact argmax (lower-idx
// tie, matches jnp.argmax) + exact softmax -> outCls, corr.
// ============================================================
__global__ __launch_bounds__(256) void k_fixup_fin(
    const float* __restrict__ lgfix,
    const int* __restrict__ wlc, const int* __restrict__ wl,
    float* __restrict__ outCls, int* __restrict__ corr)
{
    int c[6];
    int total = 0;
#pragma unroll
    for (int i = 0; i < 6; i++) { c[i] = min(wlc[i], WLNc); total += c[i]; }
    const int wid = threadIdx.x >> 6;
    const int l = threadIdx.x & 63;
    for (int g = blockIdx.x * 4 + wid; g < total; g += gridDim.x * 4) {
        int nc = 0, base = 0;
        while (nc < 5 && g >= base + c[nc]) { base += c[nc]; nc++; }
        int it = g - base;
        int col = wl[nc * WLNc + it];
        int b = col / Hh, h = col % Hh;
        const float* p = lgfix + ((long)nc * WLNc + it) * 144;
        float v0 = p[l];
        float v1 = p[l + 64];
        float v2 = (l < 16) ? p[l + 128] : -1e30f;
        float m1 = v0; int i1 = l;
        if (v1 > m1) { m1 = v1; i1 = l + 64; }
        if (v2 > m1) { m1 = v2; i1 = l + 128; }
#pragma unroll
        for (int off = 32; off; off >>= 1) {
            float o1 = __shfl_xor(m1, off);
            int oi = __shfl_xor(i1, off);
            if (o1 > m1 || (o1 == m1 && oi < i1)) { m1 = o1; i1 = oi; }
        }
        float e0 = expf(v0 - m1);
        float e1 = expf(v1 - m1);
        float e2 = (l < 16) ? expf(v2 - m1) : 0.f;
        float s = e0 + e1 + e2;
#pragma unroll
        for (int off = 32; off; off >>= 1) s += __shfl_xor(s, off);
        float inv = 1.f / s;
        int row = (b * NCc + nc) * Hh + h;
        float* op = outCls + (long)row * 144;
        op[l] = e0 * inv;
        op[l + 64] = e1 * inv;
        if (l < 16) op[l + 128] = e2 * inv;
        if (l == 0) corr[row] = i1;
    }
}

// gather window: win[(b*NC+nc)][f*H*K + h*K + k]
__global__ void k_gather(const float* __restrict__ x, const int* __restrict__ corr,
                         float* __restrict__ win)
{
    int tid = blockIdx.x * 256 + threadIdx.x;
    if (tid >= Bb * NCc * ITCc) return;
    int row = tid / ITCc, i = tid % ITCc;
    int b = row / NCc, nc = row % NCc;
    int f = i / (Hh * KWc);
    int r = i % (Hh * KWc);
    int h = r / KWc, k = r % KWc;
    int j = corr[(b * NCc + nc) * Hh + h] + k - OFFc;
    float v = 0.f;
    if (j >= 0 && j < Ww) v = x[((long)(b * DFc + f) * Hh + h) * Ww + j];
    win[tid] = v;
}

__global__ __launch_bounds__(256) void k_layernorm(
    const float* __restrict__ in, const float* __restrict__ g,
    const float* __restrict__ bta, float* __restrict__ out)
{
    __shared__ float r1[256], r2[256];
    const int row = blockIdx.x;
    const int t = threadIdx.x;
    const float* p = in + (long)row * DTc;
    float s = 0.f, sq = 0.f;
    for (int i = t; i < DTc; i += 256) {
        float v = p[i];
        s += v; sq += v * v;
    }
    r1[t] = s; r2[t] = sq;
    __syncthreads();
    for (int st = 128; st > 0; st >>= 1) {
        if (t < st) { r1[t] += r1[t + st]; r2[t] += r2[t + st]; }
        __syncthreads();
    }
    float mean = r1[0] / DTc;
    float var = r2[0] / DTc - mean * mean;
    float rstd = rsqrtf(var + EPSc);
    float* o = out + (long)row * DTc;
    for (int i = t; i < DTc; i += 256) o[i] = (p[i] - mean) * rstd * g[i] + bta[i];
}

// tiny attention: one thread per (b, head, n)
__global__ void k_attention(const float* __restrict__ qkv, const int* __restrict__ exist,
                            float* __restrict__ obuf)
{
    int idx = blockIdx.x * 256 + threadIdx.x;
    if (idx >= Bb * HEADSc * NCc) return;
    int b = idx / (HEADSc * NCc);
    int r = idx % (HEADSc * NCc);
    int hd = r / NCc, n = r % NCc;
    const float* base = qkv + (long)b * NCc * (3 * INNERc);
    const float* q = base + (long)n * (3 * INNERc) + hd * DHc;
    float s[NCc];
    for (int m = 0; m < NCc; m++) {
        const float* kp = base + (long)m * (3 * INNERc) + INNERc + hd * DHc;
        float d = 0.f;
        for (int t = 0; t < DHc; t++) d += q[t] * kp[t];
        s[m] = exist[b * NCc + m] ? d * 0.125f : -1e9f;
    }
    float mx = s[0];
    for (int m = 1; m < NCc; m++) mx = fmaxf(mx, s[m]);
    float sum = 0.f;
    for (int m = 0; m < NCc; m++) { s[m] = expf(s[m] - mx); sum += s[m]; }
    float inv = 1.f / sum;
    for (int m = 0; m < NCc; m++) s[m] *= inv;
    float* op = obuf + (long)(b * NCc + n) * INNERc + hd * DHc;
    for (int t = 0; t < DHc; t++) {
        float acc = 0.f;
        for (int m = 0; m < NCc; m++)
            acc += s[m] * base[(long)m * (3 * INNERc) + 2 * INNERc + hd * DHc + t];
        op[t] = acc;
    }
}

__global__ void k_gelu(float* __restrict__ p, int n)
{
    int tid = blockIdx.x * 256 + threadIdx.x;
    if (tid < n) {
        float v = p[tid];
        p[tid] = 0.5f * v * (1.f + erff(v * 0.70710678118654752440f));
    }
}

__global__ void k_copy4(const float4* __restrict__ s, float4* __restrict__ d, int n)
{
    int tid = blockIdx.x * 256 + threadIdx.x;
    if (tid < n) d[tid] = s[tid];
}

// scatter dec into x2; per-(b,h,f) thread, c descending, first-writer-wins per column
__global__ void k_scatter(const float* __restrict__ dec, const int* __restrict__ corr,
                          const int* __restrict__ exist, float* __restrict__ x2)
{
    int idx = blockIdx.x * 256 + threadIdx.x;
    if (idx >= Bb * Hh * DFc) return;
    int b = idx / (Hh * DFc);
    int r = idx % (Hh * DFc);
    int h = r / DFc, f = r % DFc;
    if (h >= Hh - 1) return;  // hmask
    unsigned long long m0 = 0ull, m1 = 0ull, m2 = 0ull;
    float* xrow = x2 + ((long)(b * DFc + f) * Hh + h) * Ww;
    for (int c = NCc - 1; c >= 0; c--) {
        if (!exist[b * NCc + c]) continue;
        int cr = corr[(b * NCc + c) * Hh + h];
        const float* dp = dec + (long)(b * NCc + c) * ITCc + f * (Hh * KWc) + h * KWc;
        for (int k = 0; k < KWc; k++) {
            int j = cr + k - OFFc;
            if (j < 0 || j >= Ww) continue;
            bool seen;
            if (j < 64) { unsigned long long bit = 1ull << j; seen = (m0 & bit) != 0; m0 |= bit; }
            else if (j < 128) { unsigned long long bit = 1ull << (j - 64); seen = (m1 & bit) != 0; m1 |= bit; }
            else { unsigned long long bit = 1ull << (j - 128); seen = (m2 & bit) != 0; m2 |= bit; }
            if (!seen) xrow[j] = dp[k];
        }
    }
}

extern "C" void kernel_launch(void* const* d_in, const int* in_sizes, int n_in,
                              void* d_out, int out_size, void* d_ws, size_t ws_size,
                              hipStream_t stream)
{
    const float* const* in = (const float* const*)d_in;
    const float* x = in[0];
    // input index bases: ext=1, cls=9, ext2=17, cls2=25
    const float* emb = in[33];
    const float* tok_w = in[34]; const float* tok_b = in[35];
    const float* ln1_g = in[36]; const float* ln1_b = in[37];
    const float* qkv_w = in[38];
    const float* out_w = in[39]; const float* out_b = in[40];
    const float* ln2_g = in[41]; const float* ln2_b = in[42];
    const float* ff_w1 = in[43]; const float* ff_b1 = in[44];
    const float* ff_w2 = in[45]; const float* ff_b2 = in[46];
    const float* lnf_g = in[47]; const float* lnf_b = in[48];
    const float* dec_w = in[49]; const float* dec_b = in[50];

    float* out = (float*)d_out;
    float* outExt1 = out;
    float* outCls1 = out + 55296;
    float* outExt2 = out + 4036608;
    float* outCls2 = out + 4091904;

    // ---- workspace layout (floats) ----
    const long strideB  = (long)BHc * CINc;         // 5,308,416 bf16 / plane (x)
    const long strideApl = (long)NCc * 256 * 1152;  // 1,769,472 bf16 / plane (effW)
    float* ws = (float*)d_ws;
    // hbuf region [0 .. 14,155,776):
    float* w1Tc  = ws;                 // 3,538,944 (cls w1^T)
    float* w1Te  = ws + 3538944;       // 3,538,944 (ext w1^T)
    float* effWf = ws + 7077888;       // 1,769,472 (effW fp32 [nc][256][1152])
    float* lgTn  = ws + 8847360;       // 3,981,312 (cls logits lgT[nc][col][144])
    float* hsfix = ws;                 // alias: fixup exact h (after lgT consumed)
    float* x2    = ws;                 // alias: stage-boundary x2 (first 5.3M)
    unsigned short* Apl = (unsigned short*)(ws + 14155776);   // 2 effW planes (3.54M shorts)
    // Apl2 region [17694720 .. 18481152):
    float* W2s    = ws + 17694720;            // <= 589,824 (w2*scale padded)
    float* extLg  = ws + 17694720;            // 55,296 (alias; after W2s dead)
    float* scaleE = ws + 17694720 + 589824;   // 3072
    float* shiftE = scaleE + 3072;            // 3072
    float* effB   = shiftE + 3072;            // 1536
    unsigned short* Bpl = (unsigned short*)(ws + 18481152);   // 2 planes x
    float* lgfix = ws + 18481152;             // fixup exact logits (Bpl alias, post-GEMM)
    float* windec = ws + 18481152;            // alias over Bpl
    float* tok  = windec + 1105920;
    float* ybuf = tok + 196608;
    float* qkvB = ybuf + 196608;
    float* obuf = qkvB + 589824;
    float* ffh  = obuf + 196608;
    float* scaleB = ws + 26443776;
    float* shiftB = scaleB + 3072;
    int* corrB  = (int*)(shiftB + 3072);                 // 27648
    int* existB = corrB + 27648;                         // 192
    int* wlcB   = existB + 192;                          // 8 (per-nc counts)
    int* wlB    = wlcB + 8;                              // 6*WLN = 27648
    float* win = windec;
    float* dec = windec;

    auto run_stage = [&](int be, int bc, float* oExt, float* oCls, bool stage1) {
        // scale/shift (cls kept for fixup), zero worklist counters
        k_scale_shift<<<12, 256, 0, stream>>>(in[bc + 2], in[bc + 5], in[bc + 4],
                                              in[bc + 3], in[bc + 1], scaleB, shiftB,
                                              NCc * DSc, wlcB);
        k_scale_shift<<<12, 256, 0, stream>>>(in[be + 2], in[be + 5], in[be + 4],
                                              in[be + 3], in[be + 1], scaleE, shiftE,
                                              NCc * DSc, nullptr);
        // w1 transposes -> [nc][1152][512]
        k_transpose<<<dim3(36, 16, 6), 256, 0, stream>>>(in[bc + 0], w1Tc);
        k_transpose<<<dim3(36, 16, 6), 256, 0, stream>>>(in[be + 0], w1Te);
        // effW = (w2*scale) @ w1  (fp32), cls rows 0..143 then ext rows 144..145
        k_w2s<<<2304, 256, 0, stream>>>(in[bc + 6], scaleB, W2s, 144, 192);
        gemm_nt_b<<<dim3(18, 3, 6), 256, 0, stream>>>(W2s, (long)192 * 512, w1Tc,
                                                      (long)1152 * 512, effWf,
                                                      (long)256 * 1152, 512);
        k_w2s<<<768, 256, 0, stream>>>(in[be + 6], scaleE, W2s, 2, 64);
        gemm_nt_b<<<dim3(18, 1, 6), 256, 0, stream>>>(W2s, (long)64 * 512, w1Te,
                                                      (long)1152 * 512,
                                                      effWf + (long)144 * 1152,
                                                      (long)256 * 1152, 512);
        // effB = b2 + w2 @ shift
        k_effb<<<96, 256, 0, stream>>>(in[bc + 6], in[bc + 7], shiftB,
                                       in[be + 6], in[be + 7], shiftE, effB);
        // split effW to bf16 planes, run fused head GEMM
        k_split_effw<<<6912, 256, 0, stream>>>(effWf, Apl, strideApl);
        gemm_fused<<<dim3(36, 2, 6), 256, 0, stream>>>(Apl, strideApl, Bpl, strideB,
                                                       lgTn, extLg, effB);
        // heads
        k_ext_head2<<<Bb * NCc, 256, 0, stream>>>(extLg, oExt, existB);
        k_softmax2<<<6912, 256, 0, stream>>>(lgTn, oCls, corrB, wlcB, wlB, stage1 ? 1 : 0);
        if (stage1) {
            // exact fp32 recompute (hsfix clobbers hbuf region; lgT already consumed)
            k_fixup_h<<<dim3(32, NCc, 8), 256, 0, stream>>>(x, in[bc + 0], scaleB, shiftB,
                                                            wlcB, wlB, hsfix);
            k_fixup_lg<<<dim3(9, NCc, 8), 256, 0, stream>>>(hsfix, in[bc + 6], in[bc + 7],
                                                            wlcB, wlB, lgfix);
            k_fixup_fin<<<512, 256, 0, stream>>>(lgfix, wlcB, wlB, oCls, corrB);
        }
    };

    // ======== stage 1 ========
    k_split_x<<<20736, 256, 0, stream>>>(x, Bpl, strideB);
    run_stage(1, 9, outExt1, outCls1, true);

    // gather + token projection (win clobbers lgfix/Bpl — both dead by now)
    k_gather<<<4320, 256, 0, stream>>>(x, corrB, win);
    k_tok_init<<<768, 256, 0, stream>>>(tok, tok_b, emb);
    // kc=288 (multiple of BK=16; 20 chunks x 288 = 5760)
    gemm_nt_sk<<<dim3(16, 3, 20), 256, 0, stream>>>(win, tok_w, tok, 192, DTc, ITCc, 288);

    // transformer block
    k_layernorm<<<192, 256, 0, stream>>>(tok, ln1_g, ln1_b, ybuf);
    k_bias<<<2304, 256, 0, stream>>>(qkvB, nullptr, 192, 3 * INNERc, 0);
    gemm_nt_sk<<<dim3(48, 3, 8), 256, 0, stream>>>(ybuf, qkv_w, qkvB, 192, 3 * INNERc, DTc, 128);
    k_attention<<<12, 256, 0, stream>>>(qkvB, existB, obuf);
    k_bias<<<768, 256, 0, stream>>>(tok, out_b, 192, DTc, 1);
    gemm_nt_sk<<<dim3(16, 3, 8), 256, 0, stream>>>(obuf, out_w, tok, 192, DTc, INNERc, 128);
    k_layernorm<<<192, 256, 0, stream>>>(tok, ln2_g, ln2_b, ybuf);
    k_bias<<<1536, 256, 0, stream>>>(ffh, ff_b1, 192, MLPc, 0);
    gemm_nt_sk<<<dim3(32, 3, 8), 256, 0, stream>>>(ybuf, ff_w1, ffh, 192, MLPc, DTc, 128);
    k_gelu<<<1536, 256, 0, stream>>>(ffh, 192 * MLPc);
    k_bias<<<768, 256, 0, stream>>>(tok, ff_b2, 192, DTc, 1);
    gemm_nt_sk<<<dim3(16, 3, 16), 256, 0, stream>>>(ffh, ff_w2, tok, 192, DTc, MLPc, 128);
    k_layernorm<<<192, 256, 0, stream>>>(tok, lnf_g, lnf_b, ybuf);
    // dec: full-K plain-store with fused bias (replaces k_bias init + split-K atomics)
    gemm_nt_f<<<dim3(90, 3), 256, 0, stream>>>(ybuf, dec_w, dec, dec_b, 192, ITCc, DTc);

    // scatter into x2 (copy of x); x2 aliases hbuf (stage-1 scratch dead)
    k_copy4<<<5184, 256, 0, stream>>>((const float4*)x, (float4*)x2, 1327104);
    k_scatter<<<144, 256, 0, stream>>>(dec, corrB, existB, x2);

    // ======== stage 2 ======== (dec consumed; Bpl overwrite is safe)
    k_split_x<<<20736, 256, 0, stream>>>(x2, Bpl, strideB);
    run_stage(17, 25, outExt2, outCls2, false);

    (void)in_sizes; (void)n_in; (void)out_size; (void)ws_size;
}

// Round 9
// 910.123 us; speedup vs baseline: 1.1773x; 1.1773x over previous
//
#include <hip/hip_runtime.h>
#include <math.h>

// ---- problem constants ----
#define Bb 32
#define DFc 8
#define Hh 144
#define Ww 144
#define OFFc 2
#define KWc 5
#define DSc 512
#define DTc 1024
#define NCc 6
#define HEADSc 16
#define DHc 64
#define MLPc 2048
#define CINc (DFc * Ww)        // 1152
#define ITCc (DFc * Hh * KWc)  // 5760
#define BHc (Bb * Hh)          // 4608
#define INNERc (HEADSc * DHc)  // 1024
#define EPSc 1e-5f
#define THRc 0.3f
#define WLNc 4608              // per-nc worklist capacity (max columns per nc)
#define GAPDELTA 1e-3f

typedef __attribute__((ext_vector_type(8))) short short8;
typedef __attribute__((ext_vector_type(4))) float f32x4;

// bf16 split helpers (manual RTN-even)
__device__ inline unsigned short f2bf(float v) {
    unsigned int u = __float_as_uint(v);
    unsigned int r = (u + 0x7FFFu + ((u >> 16) & 1u)) >> 16;
    return (unsigned short)r;
}
__device__ inline float bf2f(unsigned short b) {
    return __uint_as_float(((unsigned int)b) << 16);
}

// ============================================================
// Permute x(B,DF,H,W) -> Bt[n=(b*H+h)][k=(f*W+w)] and split into 2 bf16 planes.
// ============================================================
__global__ void k_split_x(const float* __restrict__ x, unsigned short* __restrict__ p,
                          long planeStride)
{
    int tid = blockIdx.x * 256 + threadIdx.x;  // = n*CIN + k
    if (tid >= BHc * CINc) return;
    int n = tid / CINc, k = tid % CINc;
    int b = n / Hh, h = n % Hh;
    int f = k / Ww, w = k % Ww;
    float v = x[((long)(b * DFc + f) * Hh + h) * Ww + w];
    unsigned short h0 = f2bf(v);
    p[tid] = h0;
    p[planeStride + tid] = f2bf(v - bf2f(h0));
}

// ============================================================
// Tiled transpose: src [nc][512][1152] -> dst [nc][1152][512]
// grid (36, 16, 6), 256 threads (32x8)
// ============================================================
__global__ __launch_bounds__(256) void k_transpose(
    const float* __restrict__ src, float* __restrict__ dst)
{
    __shared__ float t[32][33];
    const int nc = blockIdx.z;
    const int s0 = blockIdx.y * 32;
    const int k0 = blockIdx.x * 32;
    const int lx = threadIdx.x & 31, ly = threadIdx.x >> 5;
    const float* sp = src + ((long)nc * 512 + s0) * 1152 + k0;
#pragma unroll
    for (int i = 0; i < 32; i += 8)
        t[ly + i][lx] = sp[(long)(ly + i) * 1152 + lx];
    __syncthreads();
    float* dp = dst + ((long)nc * 1152 + k0) * 512 + s0;
#pragma unroll
    for (int i = 0; i < 32; i += 8)
        dp[(long)(ly + i) * 512 + lx] = t[lx][ly + i];
}

// ============================================================
// W2s[nc][Mpad][512] = (o < O) ? w2[nc][o][s] * scale[nc*512+s] : 0
// ============================================================
__global__ void k_w2s(const float* __restrict__ w2, const float* __restrict__ scale,
                      float* __restrict__ Ws, int O, int Mpad)
{
    int i = blockIdx.x * 256 + threadIdx.x;
    if (i >= NCc * Mpad * 512) return;
    int s = i & 511;
    int o = (i >> 9) % Mpad;
    int nc = i / (Mpad * 512);
    float v = 0.f;
    if (o < O) v = w2[((long)nc * O + o) * 512 + s] * scale[nc * 512 + s];
    Ws[i] = v;
}

// ============================================================
// Batched plain-store NT GEMM: C[z][m][1152-ld] = A[z][m][K] @ B[z][n][K]^T
// 64x64 tile, BK=16, grid (n/64, m/64, z). Reg-prefetch pipelined.
// ============================================================
__global__ __launch_bounds__(256) void gemm_nt_b(
    const float* __restrict__ A, long sAz,
    const float* __restrict__ Bm, long sBz,
    float* __restrict__ C, long sCz, int K)
{
    __shared__ float As[16][68];
    __shared__ float Bs[16][68];
    const int tid = threadIdx.x;
    const int n0 = blockIdx.x * 64;
    const int m0 = blockIdx.y * 64;
    const int z = blockIdx.z;
    const int lRow = tid >> 2, lCol = (tid & 3) << 2;
    const int ty = tid >> 4, tx = tid & 15;
    const float* Az = A + (long)z * sAz + (long)(m0 + lRow) * K + lCol;
    const float* Bz = Bm + (long)z * sBz + (long)(n0 + lRow) * K + lCol;

    float acc[4][4];
#pragma unroll
    for (int i = 0; i < 4; i++)
#pragma unroll
        for (int j = 0; j < 4; j++) acc[i][j] = 0.f;

    float4 av = *(const float4*)(Az);
    float4 bv = *(const float4*)(Bz);
    for (int k0 = 0; k0 < K; k0 += 16) {
        As[lCol + 0][lRow] = av.x; As[lCol + 1][lRow] = av.y;
        As[lCol + 2][lRow] = av.z; As[lCol + 3][lRow] = av.w;
        Bs[lCol + 0][lRow] = bv.x; Bs[lCol + 1][lRow] = bv.y;
        Bs[lCol + 2][lRow] = bv.z; Bs[lCol + 3][lRow] = bv.w;
        __syncthreads();
        if (k0 + 16 < K) {
            av = *(const float4*)(Az + k0 + 16);
            bv = *(const float4*)(Bz + k0 + 16);
        }
#pragma unroll
        for (int kk = 0; kk < 16; kk++) {
            float4 a = *(const float4*)&As[kk][ty * 4];
            float4 b = *(const float4*)&Bs[kk][tx * 4];
            float aa[4] = {a.x, a.y, a.z, a.w};
            float bb[4] = {b.x, b.y, b.z, b.w};
#pragma unroll
            for (int i = 0; i < 4; i++)
#pragma unroll
                for (int j = 0; j < 4; j++) acc[i][j] += aa[i] * bb[j];
        }
        __syncthreads();
    }
    const int ncol = n0 + tx * 4;
#pragma unroll
    for (int i = 0; i < 4; i++) {
        float* cp = C + (long)z * sCz + (long)(m0 + ty * 4 + i) * 1152 + ncol;
#pragma unroll
        for (int j = 0; j < 4; j++) cp[j] = acc[i][j];
    }
}

// ============================================================
// effB[nc][256]: o<144: b2c + sum_s w2c[o][s]*shiftC; o in {144,145}:
// b2e + sum_s w2e[o-144][s]*shiftE; else 0. 16-lane group per output.
// ============================================================
__global__ __launch_bounds__(256) void k_effb(
    const float* __restrict__ w2c, const float* __restrict__ b2c, const float* __restrict__ shiftC,
    const float* __restrict__ w2e, const float* __restrict__ b2e, const float* __restrict__ shiftE,
    float* __restrict__ effB)
{
    int g = blockIdx.x * 16 + (threadIdx.x >> 4);
    int lane = threadIdx.x & 15;
    if (g >= NCc * 256) return;
    int nc = g >> 8, o = g & 255;
    float d = 0.f;
    if (o < 144) {
        const float* wp = w2c + ((long)nc * 144 + o) * 512;
        const float* sp = shiftC + nc * 512;
        for (int s = lane; s < 512; s += 16) d += wp[s] * sp[s];
    } else if (o < 146) {
        const float* wp = w2e + ((long)nc * 2 + (o - 144)) * 512;
        const float* sp = shiftE + nc * 512;
        for (int s = lane; s < 512; s += 16) d += wp[s] * sp[s];
    }
#pragma unroll
    for (int off = 8; off; off >>= 1) d += __shfl_xor(d, off);
    if (lane == 0) {
        float b = (o < 144) ? b2c[nc * 144 + o] : ((o < 146) ? b2e[nc * 2 + o - 144] : 0.f);
        effB[g] = d + b;
    }
}

// ============================================================
// Split effW fp32 [nc][256][1152] (rows >=208 garbage) into 2 bf16 planes
// ============================================================
__global__ void k_split_effw(const float* __restrict__ effW, unsigned short* __restrict__ p,
                             long planeStride)
{
    int i = blockIdx.x * 256 + threadIdx.x;  // over 6*256*1152 = 1,769,472
    if (i >= NCc * 256 * 1152) return;
    int o = (i / 1152) & 255;
    float v = (o < 208) ? effW[i] : 0.f;
    unsigned short h0 = f2bf(v);
    p[i] = h0;
    p[planeStride + i] = f2bf(v - bf2f(h0));
}

// ============================================================
// Fused head GEMM (MFMA, split-bf16, 3 products): per nc,
// logits[o][col] = effW[nc][o][:] . X[col][:]  (K=1152)
// grid (36, 2, 6), 128x128 tiles, BK=32, 2-phase dbuf + T2 both-sides swizzle.
// Epilogue: o<144 -> cls lgT[nc][col][o]; o==144 -> ext logits extLg[nc][col][2].
// ============================================================
__global__ __launch_bounds__(256) void gemm_fused(
    const unsigned short* __restrict__ Ag, long strideA,
    const unsigned short* __restrict__ Bg, long strideB,
    float* __restrict__ lgT, float* __restrict__ extLg,
    const float* __restrict__ effB)
{
    constexpr int K = 1152;
    constexpr int PAt[3] = {0, 0, 1};
    constexpr int PBt[3] = {0, 1, 0};
    __shared__ __align__(16) unsigned short As[2][2][128 * 32];
    __shared__ __align__(16) unsigned short Bs[2][2][128 * 32];
    const int tid = threadIdx.x;
    const int w = tid >> 6;
    const int l = tid & 63;
    const int quad = l >> 4, l15 = l & 15;
    const int z = blockIdx.z;
    const int m0 = blockIdx.y * 128, n0 = blockIdx.x * 128;
    const int rw = (w >> 1) * 64, cw = (w & 1) * 64;

    f32x4 acc[4][4];
#pragma unroll
    for (int i = 0; i < 4; i++)
#pragma unroll
        for (int j = 0; j < 4; j++) acc[i][j] = (f32x4){0.f, 0.f, 0.f, 0.f};

    const int srow = w * 32;
    const int lr = l >> 2;
    const int lc = ((l & 3) ^ ((lr >> 1) & 3)) * 8;  // pre-swizzled source slot
    const unsigned short* gA[2];
    const unsigned short* gB[2];
#pragma unroll
    for (int p = 0; p < 2; p++) {
        gA[p] = Ag + (long)p * strideA + ((long)(z * 256 + m0 + srow + lr)) * K + lc;
        gB[p] = Bg + (long)p * strideB + ((long)(n0 + srow + lr)) * K + lc;
    }
    const int ldsOff0 = srow * 32;
    const int ldsOff1 = (srow + 16) * 32;
    const int rdoff = (quad ^ ((l15 >> 1) & 3)) * 8;  // swizzled read slot

    auto STAGE = [&](int buf, int k0) {
#pragma unroll
        for (int p = 0; p < 2; p++) {
            __builtin_amdgcn_global_load_lds(
                (const __attribute__((address_space(1))) void*)(gA[p] + k0),
                (__attribute__((address_space(3))) void*)&As[buf][p][ldsOff0], 16, 0, 0);
            __builtin_amdgcn_global_load_lds(
                (const __attribute__((address_space(1))) void*)(gA[p] + 16 * K + k0),
                (__attribute__((address_space(3))) void*)&As[buf][p][ldsOff1], 16, 0, 0);
            __builtin_amdgcn_global_load_lds(
                (const __attribute__((address_space(1))) void*)(gB[p] + k0),
                (__attribute__((address_space(3))) void*)&Bs[buf][p][ldsOff0], 16, 0, 0);
            __builtin_amdgcn_global_load_lds(
                (const __attribute__((address_space(1))) void*)(gB[p] + 16 * K + k0),
                (__attribute__((address_space(3))) void*)&Bs[buf][p][ldsOff1], 16, 0, 0);
        }
    };

    const int nk = K >> 5;  // 36
    STAGE(0, 0);
    __syncthreads();
    int cur = 0;
    for (int t = 0; t < nk; ++t) {
        if (t + 1 < nk) STAGE(cur ^ 1, (t + 1) << 5);

        short8 af[2][4], bf[2][4];
#pragma unroll
        for (int p = 0; p < 2; p++)
#pragma unroll
            for (int i = 0; i < 4; i++) {
                af[p][i] = *(const short8*)&As[cur][p][(rw + i * 16 + l15) * 32 + rdoff];
                bf[p][i] = *(const short8*)&Bs[cur][p][(cw + i * 16 + l15) * 32 + rdoff];
            }
#pragma unroll
        for (int t2 = 0; t2 < 3; t2++) {
            const int pa = PAt[t2], pb = PBt[t2];
#pragma unroll
            for (int i = 0; i < 4; i++)
#pragma unroll
                for (int j = 0; j < 4; j++)
                    acc[i][j] = __builtin_amdgcn_mfma_f32_16x16x32_bf16(
                        af[pa][i], bf[pb][j], acc[i][j], 0, 0, 0);
        }
        __syncthreads();
        cur ^= 1;
    }

#pragma unroll
    for (int i = 0; i < 4; i++) {
        int ob = m0 + rw + i * 16 + quad * 4;
        if (ob < 144) {
            float4 bb = *(const float4*)(effB + z * 256 + ob);
#pragma unroll
            for (int j = 0; j < 4; j++) {
                int col = n0 + cw + j * 16 + l15;
                float4 v = make_float4(acc[i][j][0] + bb.x, acc[i][j][1] + bb.y,
                                       acc[i][j][2] + bb.z, acc[i][j][3] + bb.w);
                *(float4*)(lgT + ((long)(z * BHc + col)) * 144 + ob) = v;
            }
        } else if (ob == 144) {
            float b0 = effB[z * 256 + 144];
            float b1 = effB[z * 256 + 145];
#pragma unroll
            for (int j = 0; j < 4; j++) {
                int col = n0 + cw + j * 16 + l15;
                float* ep = extLg + ((long)z * BHc + col) * 2;
                ep[0] = acc[i][j][0] + b0;
                ep[1] = acc[i][j][1] + b1;
            }
        }
    }
}

// ============================================================
// Split-K NT GEMM, PARTIAL-STORE (no atomics): Cpart[z][m][n] = partial sum
// over k-chunk z. 64x64 tile, BK=16, reg-prefetch pipelined.
// kc MUST be a multiple of 16.
// ============================================================
__global__ __launch_bounds__(256) void gemm_nt_p(
    const float* __restrict__ A, const float* __restrict__ Bm, float* __restrict__ Cpart,
    int M, int N, int K, int kc)
{
    __shared__ float As[16][68];
    __shared__ float Bs[16][68];
    const int tid = threadIdx.x;
    const int n0 = blockIdx.x * 64;
    const int m0 = blockIdx.y * 64;
    const int ks = blockIdx.z * kc;
    const int ke = min(K, ks + kc);
    const int lRow = tid >> 2, lCol = (tid & 3) << 2;
    const int ty = tid >> 4, tx = tid & 15;
    const float* Ap = A + (long)(m0 + lRow) * K + lCol;
    const float* Bp = Bm + (long)(n0 + lRow) * K + lCol;

    float acc[4][4];
#pragma unroll
    for (int i = 0; i < 4; i++)
#pragma unroll
        for (int j = 0; j < 4; j++) acc[i][j] = 0.f;

    float4 av = *(const float4*)(Ap + ks);
    float4 bv = *(const float4*)(Bp + ks);
    for (int k0 = ks; k0 < ke; k0 += 16) {
        As[lCol + 0][lRow] = av.x; As[lCol + 1][lRow] = av.y;
        As[lCol + 2][lRow] = av.z; As[lCol + 3][lRow] = av.w;
        Bs[lCol + 0][lRow] = bv.x; Bs[lCol + 1][lRow] = bv.y;
        Bs[lCol + 2][lRow] = bv.z; Bs[lCol + 3][lRow] = bv.w;
        __syncthreads();
        if (k0 + 16 < ke) {
            av = *(const float4*)(Ap + k0 + 16);
            bv = *(const float4*)(Bp + k0 + 16);
        }
#pragma unroll
        for (int kk = 0; kk < 16; kk++) {
            float4 a = *(const float4*)&As[kk][ty * 4];
            float4 b = *(const float4*)&Bs[kk][tx * 4];
            float aa[4] = {a.x, a.y, a.z, a.w};
            float bb[4] = {b.x, b.y, b.z, b.w};
#pragma unroll
            for (int i = 0; i < 4; i++)
#pragma unroll
                for (int j = 0; j < 4; j++) acc[i][j] += aa[i] * bb[j];
        }
        __syncthreads();
    }
    const int ncol = n0 + tx * 4;
    float* base = Cpart + (long)blockIdx.z * M * N;
#pragma unroll
    for (int i = 0; i < 4; i++) {
        float* cp = base + (long)(m0 + ty * 4 + i) * N + ncol;
        cp[0] = acc[i][0];
        cp[1] = acc[i][1];
        cp[2] = acc[i][2];
        cp[3] = acc[i][3];
    }
}

// ============================================================
// Reduce partials + fused epilogue.
// mode 0: C = bias + sum            (bias may be null -> 0)
// mode 1: C += bias + sum           (residual add)
// mode 2: C = bias + emb[(row%NC)*N+n] + sum   (tok init fused)
// mode 3: C = gelu(bias + sum)      (ff1 + gelu fused)
// ============================================================
__global__ void k_reduce(const float* __restrict__ Cpart, float* __restrict__ C,
                         const float* __restrict__ bias, const float* __restrict__ emb,
                         int MN, int N, int Z, int mode)
{
    int idx = blockIdx.x * 256 + threadIdx.x;
    if (idx >= MN) return;
    int n = idx % N;
    float s = 0.f;
    for (int z = 0; z < Z; z++) s += Cpart[(long)z * MN + idx];
    float b = bias ? bias[n] : 0.f;
    if (mode == 2) { int row = idx / N; b += emb[(row % NCc) * N + n]; }
    float v = s + b;
    if (mode == 3) v = 0.5f * v * (1.f + erff(v * 0.70710678118654752440f));
    if (mode == 1) C[idx] += v;
    else C[idx] = v;
}

// ============================================================
// Full-K NT GEMM, plain store + bias: C[m][n] = A@B^T + bias[n].
// 64x64 tile, BK=16, reg-prefetch pipelined. grid (N/64, M/64).
// ============================================================
__global__ __launch_bounds__(256) void gemm_nt_f(
    const float* __restrict__ A, const float* __restrict__ Bm, float* __restrict__ C,
    const float* __restrict__ bias, int M, int N, int K)
{
    __shared__ float As[16][68];
    __shared__ float Bs[16][68];
    const int tid = threadIdx.x;
    const int n0 = blockIdx.x * 64;
    const int m0 = blockIdx.y * 64;
    const int lRow = tid >> 2, lCol = (tid & 3) << 2;
    const int ty = tid >> 4, tx = tid & 15;
    const float* Ap = A + (long)(m0 + lRow) * K + lCol;
    const float* Bp = Bm + (long)(n0 + lRow) * K + lCol;

    float acc[4][4];
#pragma unroll
    for (int i = 0; i < 4; i++)
#pragma unroll
        for (int j = 0; j < 4; j++) acc[i][j] = 0.f;

    float4 av = *(const float4*)(Ap);
    float4 bv = *(const float4*)(Bp);
    for (int k0 = 0; k0 < K; k0 += 16) {
        As[lCol + 0][lRow] = av.x; As[lCol + 1][lRow] = av.y;
        As[lCol + 2][lRow] = av.z; As[lCol + 3][lRow] = av.w;
        Bs[lCol + 0][lRow] = bv.x; Bs[lCol + 1][lRow] = bv.y;
        Bs[lCol + 2][lRow] = bv.z; Bs[lCol + 3][lRow] = bv.w;
        __syncthreads();
        if (k0 + 16 < K) {
            av = *(const float4*)(Ap + k0 + 16);
            bv = *(const float4*)(Bp + k0 + 16);
        }
#pragma unroll
        for (int kk = 0; kk < 16; kk++) {
            float4 a = *(const float4*)&As[kk][ty * 4];
            float4 b = *(const float4*)&Bs[kk][tx * 4];
            float aa[4] = {a.x, a.y, a.z, a.w};
            float bb[4] = {b.x, b.y, b.z, b.w};
#pragma unroll
            for (int i = 0; i < 4; i++)
#pragma unroll
                for (int j = 0; j < 4; j++) acc[i][j] += aa[i] * bb[j];
        }
        __syncthreads();
    }
    const int ncol = n0 + tx * 4;
    float4 bb4 = *(const float4*)(bias + ncol);
#pragma unroll
    for (int i = 0; i < 4; i++) {
        int row = m0 + ty * 4 + i;
        float* cp = C + (long)row * N + ncol;
        cp[0] = acc[i][0] + bb4.x;
        cp[1] = acc[i][1] + bb4.y;
        cp[2] = acc[i][2] + bb4.z;
        cp[3] = acc[i][3] + bb4.w;
    }
}

// scale = g*rsqrt(vr+eps); shift = (b1-mu)*scale + bt; optionally zero worklist cnts
__global__ void k_scale_shift(const float* __restrict__ g, const float* __restrict__ vr,
                              const float* __restrict__ mu, const float* __restrict__ bt,
                              const float* __restrict__ b1,
                              float* __restrict__ scale, float* __restrict__ shift, int n,
                              int* __restrict__ wlc)
{
    int i = blockIdx.x * 256 + threadIdx.x;
    if (wlc && i < 8) wlc[i] = 0;
    if (i >= n) return;
    float sc = g[i] * rsqrtf(vr[i] + EPSc);
    scale[i] = sc;
    shift[i] = (b1[i] - mu[i]) * sc + bt[i];
}

// ext head from precomputed logits: softmax (O=2) + exist reduction
__global__ __launch_bounds__(256) void k_ext_head2(
    const float* __restrict__ extLg, float* __restrict__ outExt, int* __restrict__ exist)
{
    __shared__ float red[256];
    const int bc = blockIdx.x;
    const int b = bc / NCc, nc = bc % NCc;
    const int h = threadIdx.x;
    float p0 = 0.f;
    if (h < Hh) {
        const int col = b * Hh + h;
        const float* ep = extLg + ((long)nc * BHc + col) * 2;
        float lg0 = ep[0], lg1 = ep[1];
        float mx = fmaxf(lg0, lg1);
        float e0 = expf(lg0 - mx), e1 = expf(lg1 - mx);
        float inv = 1.f / (e0 + e1);
        p0 = e0 * inv;
        float* op = outExt + ((long)bc * Hh + h) * 2;
        op[0] = p0;
        op[1] = e1 * inv;
    }
    red[threadIdx.x] = p0;
    __syncthreads();
    for (int st = 128; st > 0; st >>= 1) {
        if (threadIdx.x < st) red[threadIdx.x] += red[threadIdx.x + st];
        __syncthreads();
    }
    if (threadIdx.x == 0) exist[bc] = (red[0] / Hh > THRc) ? 1 : 0;
}

// ============================================================
// wave-per-column softmax over lgT[nc][col][144]; top-2 gap flagging (stage1),
// bucketed per-nc worklist: wlc[nc] count, wl[nc*WLN + ix] = col.
// ============================================================
__global__ __launch_bounds__(256) void k_softmax2(
    const float* __restrict__ lgT, float* __restrict__ outCls, int* __restrict__ corr,
    int* __restrict__ wlc, int* __restrict__ wl, int stage1)
{
    int wg = blockIdx.x * 4 + (threadIdx.x >> 6);
    int l = threadIdx.x & 63;
    int nc = wg / BHc, col = wg % BHc;
    int b = col / Hh, h = col % Hh;
    const float* p = lgT + ((long)nc * BHc + col) * 144;
    float v0 = p[l];
    float v1 = p[l + 64];
    float v2 = (l < 16) ? p[l + 128] : -1e30f;
    // per-lane top2 (lower idx wins ties)
    float m1 = v0, m2; int i1 = l;
    if (v1 > m1) { m2 = m1; m1 = v1; i1 = l + 64; } else m2 = v1;
    if (v2 > m1) { m2 = m1; m1 = v2; i1 = l + 128; } else m2 = fmaxf(m2, v2);
    // butterfly top2 merge across 64 lanes
#pragma unroll
    for (int off = 32; off; off >>= 1) {
        float o1 = __shfl_xor(m1, off);
        float o2 = __shfl_xor(m2, off);
        int oi = __shfl_xor(i1, off);
        if (o1 > m1 || (o1 == m1 && oi < i1)) { m2 = fmaxf(m1, o2); m1 = o1; i1 = oi; }
        else m2 = fmaxf(m2, o1);
    }
    float e0 = expf(v0 - m1);
    float e1 = expf(v1 - m1);
    float e2 = (l < 16) ? expf(v2 - m1) : 0.f;
    float s = e0 + e1 + e2;
#pragma unroll
    for (int off = 32; off; off >>= 1) s += __shfl_xor(s, off);
    float inv = 1.f / s;
    int row = (b * NCc + nc) * Hh + h;
    float* op = outCls + (long)row * 144;
    op[l] = e0 * inv;
    op[l + 64] = e1 * inv;
    if (l < 16) op[l + 128] = e2 * inv;
    if (l == 0) {
        corr[row] = i1;
        if (stage1 && (m1 - m2) < GAPDELTA) {
            int ix = atomicAdd(&wlc[nc], 1);
            if (ix < WLNc) wl[nc * WLNc + ix] = col;
        }
    }
}

// ============================================================
// fixup phase A: exact fp32 h for flagged items.
// ============================================================
__global__ __launch_bounds__(256) void k_fixup_h(
    const float* __restrict__ x, const float* __restrict__ w1,
    const float* __restrict__ scale, const float* __restrict__ shift,
    const int* __restrict__ wlc, const int* __restrict__ wl,
    float* __restrict__ hsfix)
{
    const int nc = blockIdx.y;
    const int cnt = min(wlc[nc], WLNc);
    const int chunk = blockIdx.z;  // 0..7
    if (chunk >= cnt) return;
    const int t = threadIdx.x;
    const int r = t >> 4;          // 0..15
    const int lane16 = t & 15;
    const int s = blockIdx.x * 16 + r;  // 0..511
    const float* wp = w1 + ((long)(nc * 512 + s)) * CINc + lane16 * 4;
    float4 wr[18];
#pragma unroll
    for (int i = 0; i < 18; i++) wr[i] = *(const float4*)(wp + 64 * i);
    const float sc = scale[nc * 512 + s];
    const float sh = shift[nc * 512 + s];
    int xoff[18];
#pragma unroll
    for (int i = 0; i < 18; i++) {
        int k = lane16 * 4 + 64 * i;
        xoff[i] = (k / Ww) * (Hh * Ww) + (k % Ww);
    }
    for (int it = chunk; it < cnt; it += 8) {
        int col = wl[nc * WLNc + it];
        int b = col / Hh, h = col % Hh;
        const float* xb = x + (long)b * (DFc * Hh * Ww) + h * Ww;
        float d = 0.f;
#pragma unroll
        for (int i = 0; i < 18; i++) {
            float4 xv = *(const float4*)(xb + xoff[i]);
            d += wr[i].x * xv.x + wr[i].y * xv.y + wr[i].z * xv.z + wr[i].w * xv.w;
        }
#pragma unroll
        for (int off = 8; off; off >>= 1) d += __shfl_xor(d, off);
        if (lane16 == 0) hsfix[((long)nc * WLNc + it) * 512 + s] = d * sc + sh;
    }
}

// ============================================================
// fixup phase B: exact logits lgfix[nc][item][144] = w2 @ hsfix + b2.
// ============================================================
__global__ __launch_bounds__(256) void k_fixup_lg(
    const float* __restrict__ hsfix, const float* __restrict__ w2,
    const float* __restrict__ b2,
    const int* __restrict__ wlc, const int* __restrict__ wl,
    float* __restrict__ lgfix)
{
    const int nc = blockIdx.y;
    const int cnt = min(wlc[nc], WLNc);
    const int chunk = blockIdx.z;
    if (chunk >= cnt) return;
    const int t = threadIdx.x;
    const int r = t >> 4;
    const int lane16 = t & 15;
    const int o = blockIdx.x * 16 + r;  // 0..143
    const float* wp = w2 + ((long)(nc * 144 + o)) * 512 + lane16 * 4;
    float4 wr[8];
#pragma unroll
    for (int i = 0; i < 8; i++) wr[i] = *(const float4*)(wp + 64 * i);
    const float bb = b2[nc * 144 + o];
    for (int it = chunk; it < cnt; it += 8) {
        const float* hp = hsfix + ((long)nc * WLNc + it) * 512 + lane16 * 4;
        float d = 0.f;
#pragma unroll
        for (int i = 0; i < 8; i++) {
            float4 hv = *(const float4*)(hp + 64 * i);
            d += wr[i].x * hv.x + wr[i].y * hv.y + wr[i].z * hv.z + wr[i].w * hv.w;
        }
#pragma unroll
        for (int off = 8; off; off >>= 1) d += __shfl_xor(d, off);
        if (lane16 == 0) lgfix[((long)nc * WLNc + it) * 144 + o] = d + bb;
    }
}

// ============================================================
// fixup phase C: per flagged item (one wave each): exact argmax (lower-idx
// tie, matches jnp.argmax) + exact softmax -> outCls, corr.
// ============================================================
__global__ __launch_bounds__(256) void k_fixup_fin(
    const float* __restrict__ lgfix,
    const int* __restrict__ wlc, const int* __restrict__ wl,
    float* __restrict__ outCls, int* __restrict__ corr)
{
    int c[6];
    int total = 0;
#pragma unroll
    for (int i = 0; i < 6; i++) { c[i] = min(wlc[i], WLNc); total += c[i]; }
    const int wid = threadIdx.x >> 6;
    const int l = threadIdx.x & 63;
    for (int g = blockIdx.x * 4 + wid; g < total; g += gridDim.x * 4) {
        int nc = 0, base = 0;
        while (nc < 5 && g >= base + c[nc]) { base += c[nc]; nc++; }
        int it = g - base;
        int col = wl[nc * WLNc + it];
        int b = col / Hh, h = col % Hh;
        const float* p = lgfix + ((long)nc * WLNc + it) * 144;
        float v0 = p[l];
        float v1 = p[l + 64];
        float v2 = (l < 16) ? p[l + 128] : -1e30f;
        float m1 = v0; int i1 = l;
        if (v1 > m1) { m1 = v1; i1 = l + 64; }
        if (v2 > m1) { m1 = v2; i1 = l + 128; }
#pragma unroll
        for (int off = 32; off; off >>= 1) {
            float o1 = __shfl_xor(m1, off);
            int oi = __shfl_xor(i1, off);
            if (o1 > m1 || (o1 == m1 && oi < i1)) { m1 = o1; i1 = oi; }
        }
        float e0 = expf(v0 - m1);
        float e1 = expf(v1 - m1);
        float e2 = (l < 16) ? expf(v2 - m1) : 0.f;
        float s = e0 + e1 + e2;
#pragma unroll
        for (int off = 32; off; off >>= 1) s += __shfl_xor(s, off);
        float inv = 1.f / s;
        int row = (b * NCc + nc) * Hh + h;
        float* op = outCls + (long)row * 144;
        op[l] = e0 * inv;
        op[l + 64] = e1 * inv;
        if (l < 16) op[l + 128] = e2 * inv;
        if (l == 0) corr[row] = i1;
    }
}

// gather window: win[(b*NC+nc)][f*H*K + h*K + k]
__global__ void k_gather(const float* __restrict__ x, const int* __restrict__ corr,
                         float* __restrict__ win)
{
    int tid = blockIdx.x * 256 + threadIdx.x;
    if (tid >= Bb * NCc * ITCc) return;
    int row = tid / ITCc, i = tid % ITCc;
    int b = row / NCc, nc = row % NCc;
    int f = i / (Hh * KWc);
    int r = i % (Hh * KWc);
    int h = r / KWc, k = r % KWc;
    int j = corr[(b * NCc + nc) * Hh + h] + k - OFFc;
    float v = 0.f;
    if (j >= 0 && j < Ww) v = x[((long)(b * DFc + f) * Hh + h) * Ww + j];
    win[tid] = v;
}

__global__ __launch_bounds__(256) void k_layernorm(
    const float* __restrict__ in, const float* __restrict__ g,
    const float* __restrict__ bta, float* __restrict__ out)
{
    __shared__ float r1[256], r2[256];
    const int row = blockIdx.x;
    const int t = threadIdx.x;
    const float* p = in + (long)row * DTc;
    float s = 0.f, sq = 0.f;
    for (int i = t; i < DTc; i += 256) {
        float v = p[i];
        s += v; sq += v * v;
    }
    r1[t] = s; r2[t] = sq;
    __syncthreads();
    for (int st = 128; st > 0; st >>= 1) {
        if (t < st) { r1[t] += r1[t + st]; r2[t] += r2[t + st]; }
        __syncthreads();
    }
    float mean = r1[0] / DTc;
    float var = r2[0] / DTc - mean * mean;
    float rstd = rsqrtf(var + EPSc);
    float* o = out + (long)row * DTc;
    for (int i = t; i < DTc; i += 256) o[i] = (p[i] - mean) * rstd * g[i] + bta[i];
}

// tiny attention: one thread per (b, head, n)
__global__ void k_attention(const float* __restrict__ qkv, const int* __restrict__ exist,
                            float* __restrict__ obuf)
{
    int idx = blockIdx.x * 256 + threadIdx.x;
    if (idx >= Bb * HEADSc * NCc) return;
    int b = idx / (HEADSc * NCc);
    int r = idx % (HEADSc * NCc);
    int hd = r / NCc, n = r % NCc;
    const float* base = qkv + (long)b * NCc * (3 * INNERc);
    const float* q = base + (long)n * (3 * INNERc) + hd * DHc;
    float s[NCc];
    for (int m = 0; m < NCc; m++) {
        const float* kp = base + (long)m * (3 * INNERc) + INNERc + hd * DHc;
        float d = 0.f;
        for (int t = 0; t < DHc; t++) d += q[t] * kp[t];
        s[m] = exist[b * NCc + m] ? d * 0.125f : -1e9f;
    }
    float mx = s[0];
    for (int m = 1; m < NCc; m++) mx = fmaxf(mx, s[m]);
    float sum = 0.f;
    for (int m = 0; m < NCc; m++) { s[m] = expf(s[m] - mx); sum += s[m]; }
    float inv = 1.f / sum;
    for (int m = 0; m < NCc; m++) s[m] *= inv;
    float* op = obuf + (long)(b * NCc + n) * INNERc + hd * DHc;
    for (int t = 0; t < DHc; t++) {
        float acc = 0.f;
        for (int m = 0; m < NCc; m++)
            acc += s[m] * base[(long)m * (3 * INNERc) + 2 * INNERc + hd * DHc + t];
        op[t] = acc;
    }
}

__global__ void k_copy4(const float4* __restrict__ s, float4* __restrict__ d, int n)
{
    int tid = blockIdx.x * 256 + threadIdx.x;
    if (tid < n) d[tid] = s[tid];
}

// scatter dec into x2; per-(b,h,f) thread, c descending, first-writer-wins per column
__global__ void k_scatter(const float* __restrict__ dec, const int* __restrict__ corr,
                          const int* __restrict__ exist, float* __restrict__ x2)
{
    int idx = blockIdx.x * 256 + threadIdx.x;
    if (idx >= Bb * Hh * DFc) return;
    int b = idx / (Hh * DFc);
    int r = idx % (Hh * DFc);
    int h = r / DFc, f = r % DFc;
    if (h >= Hh - 1) return;  // hmask
    unsigned long long m0 = 0ull, m1 = 0ull, m2 = 0ull;
    float* xrow = x2 + ((long)(b * DFc + f) * Hh + h) * Ww;
    for (int c = NCc - 1; c >= 0; c--) {
        if (!exist[b * NCc + c]) continue;
        int cr = corr[(b * NCc + c) * Hh + h];
        const float* dp = dec + (long)(b * NCc + c) * ITCc + f * (Hh * KWc) + h * KWc;
        for (int k = 0; k < KWc; k++) {
            int j = cr + k - OFFc;
            if (j < 0 || j >= Ww) continue;
            bool seen;
            if (j < 64) { unsigned long long bit = 1ull << j; seen = (m0 & bit) != 0; m0 |= bit; }
            else if (j < 128) { unsigned long long bit = 1ull << (j - 64); seen = (m1 & bit) != 0; m1 |= bit; }
            else { unsigned long long bit = 1ull << (j - 128); seen = (m2 & bit) != 0; m2 |= bit; }
            if (!seen) xrow[j] = dp[k];
        }
    }
}

extern "C" void kernel_launch(void* const* d_in, const int* in_sizes, int n_in,
                              void* d_out, int out_size, void* d_ws, size_t ws_size,
                              hipStream_t stream)
{
    const float* const* in = (const float* const*)d_in;
    const float* x = in[0];
    // input index bases: ext=1, cls=9, ext2=17, cls2=25
    const float* emb = in[33];
    const float* tok_w = in[34]; const float* tok_b = in[35];
    const float* ln1_g = in[36]; const float* ln1_b = in[37];
    const float* qkv_w = in[38];
    const float* out_w = in[39]; const float* out_b = in[40];
    const float* ln2_g = in[41]; const float* ln2_b = in[42];
    const float* ff_w1 = in[43]; const float* ff_b1 = in[44];
    const float* ff_w2 = in[45]; const float* ff_b2 = in[46];
    const float* lnf_g = in[47]; const float* lnf_b = in[48];
    const float* dec_w = in[49]; const float* dec_b = in[50];

    float* out = (float*)d_out;
    float* outExt1 = out;
    float* outCls1 = out + 55296;
    float* outExt2 = out + 4036608;
    float* outCls2 = out + 4091904;

    // ---- workspace layout (floats) ----
    const long strideB  = (long)BHc * CINc;         // 5,308,416 bf16 / plane (x)
    const long strideApl = (long)NCc * 256 * 1152;  // 1,769,472 bf16 / plane (effW)
    float* ws = (float*)d_ws;
    // hbuf region [0 .. 14,155,776):
    float* w1Tc  = ws;                 // 3,538,944 (cls w1^T)
    float* w1Te  = ws + 3538944;       // 3,538,944 (ext w1^T)
    float* effWf = ws + 7077888;       // 1,769,472 (effW fp32 [nc][256][1152])
    float* lgTn  = ws + 8847360;       // 3,981,312 (cls logits lgT[nc][col][144])
    float* hsfix = ws;                 // alias: fixup exact h (after lgT consumed)
    float* x2    = ws;                 // alias: stage-boundary x2 (first 5.3M)
    float* Cpart = ws;                 // alias: split-K partials (transformer; max 4.72M f)
    unsigned short* Apl = (unsigned short*)(ws + 14155776);   // 2 effW planes (3.54M shorts)
    // Apl2 region [17694720 .. 18481152):
    float* W2s    = ws + 17694720;            // <= 589,824 (w2*scale padded)
    float* extLg  = ws + 17694720;            // 55,296 (alias; after W2s dead)
    float* scaleE = ws + 17694720 + 589824;   // 3072
    float* shiftE = scaleE + 3072;            // 3072
    float* effB   = shiftE + 3072;            // 1536
    unsigned short* Bpl = (unsigned short*)(ws + 18481152);   // 2 planes x
    float* lgfix = ws + 18481152;             // fixup exact logits (Bpl alias, post-GEMM)
    float* windec = ws + 18481152;            // alias over Bpl
    float* tok  = windec + 1105920;
    float* ybuf = tok + 196608;
    float* qkvB = ybuf + 196608;
    float* obuf = qkvB + 589824;
    float* ffh  = obuf + 196608;
    float* scaleB = ws + 26443776;
    float* shiftB = scaleB + 3072;
    int* corrB  = (int*)(shiftB + 3072);                 // 27648
    int* existB = corrB + 27648;                         // 192
    int* wlcB   = existB + 192;                          // 8 (per-nc counts)
    int* wlB    = wlcB + 8;                              // 6*WLN = 27648
    float* win = windec;
    float* dec = windec;

    auto run_stage = [&](int be, int bc, float* oExt, float* oCls, bool stage1) {
        // scale/shift (cls kept for fixup), zero worklist counters
        k_scale_shift<<<12, 256, 0, stream>>>(in[bc + 2], in[bc + 5], in[bc + 4],
                                              in[bc + 3], in[bc + 1], scaleB, shiftB,
                                              NCc * DSc, wlcB);
        k_scale_shift<<<12, 256, 0, stream>>>(in[be + 2], in[be + 5], in[be + 4],
                                              in[be + 3], in[be + 1], scaleE, shiftE,
                                              NCc * DSc, nullptr);
        // w1 transposes -> [nc][1152][512]
        k_transpose<<<dim3(36, 16, 6), 256, 0, stream>>>(in[bc + 0], w1Tc);
        k_transpose<<<dim3(36, 16, 6), 256, 0, stream>>>(in[be + 0], w1Te);
        // effW = (w2*scale) @ w1  (fp32), cls rows 0..143 then ext rows 144..145
        k_w2s<<<2304, 256, 0, stream>>>(in[bc + 6], scaleB, W2s, 144, 192);
        gemm_nt_b<<<dim3(18, 3, 6), 256, 0, stream>>>(W2s, (long)192 * 512, w1Tc,
                                                      (long)1152 * 512, effWf,
                                                      (long)256 * 1152, 512);
        k_w2s<<<768, 256, 0, stream>>>(in[be + 6], scaleE, W2s, 2, 64);
        gemm_nt_b<<<dim3(18, 1, 6), 256, 0, stream>>>(W2s, (long)64 * 512, w1Te,
                                                      (long)1152 * 512,
                                                      effWf + (long)144 * 1152,
                                                      (long)256 * 1152, 512);
        // effB = b2 + w2 @ shift
        k_effb<<<96, 256, 0, stream>>>(in[bc + 6], in[bc + 7], shiftB,
                                       in[be + 6], in[be + 7], shiftE, effB);
        // split effW to bf16 planes, run fused head GEMM
        k_split_effw<<<6912, 256, 0, stream>>>(effWf, Apl, strideApl);
        gemm_fused<<<dim3(36, 2, 6), 256, 0, stream>>>(Apl, strideApl, Bpl, strideB,
                                                       lgTn, extLg, effB);
        // heads
        k_ext_head2<<<Bb * NCc, 256, 0, stream>>>(extLg, oExt, existB);
        k_softmax2<<<6912, 256, 0, stream>>>(lgTn, oCls, corrB, wlcB, wlB, stage1 ? 1 : 0);
        if (stage1) {
            // exact fp32 recompute (hsfix clobbers hbuf region; lgT already consumed)
            k_fixup_h<<<dim3(32, NCc, 8), 256, 0, stream>>>(x, in[bc + 0], scaleB, shiftB,
                                                            wlcB, wlB, hsfix);
            k_fixup_lg<<<dim3(9, NCc, 8), 256, 0, stream>>>(hsfix, in[bc + 6], in[bc + 7],
                                                            wlcB, wlB, lgfix);
            k_fixup_fin<<<512, 256, 0, stream>>>(lgfix, wlcB, wlB, oCls, corrB);
        }
    };

    // ======== stage 1 ========
    k_split_x<<<20736, 256, 0, stream>>>(x, Bpl, strideB);
    run_stage(1, 9, outExt1, outCls1, true);

    // gather + token projection (win clobbers lgfix/Bpl — both dead by now).
    // Cpart lives in the hbuf region (dead until k_copy4 writes x2 after dec).
    k_gather<<<4320, 256, 0, stream>>>(x, corrB, win);
    // tok: 20 chunks x kc=288 (mult of 16), partial-store + reduce (fuses tok_b+emb)
    gemm_nt_p<<<dim3(16, 3, 20), 256, 0, stream>>>(win, tok_w, Cpart, 192, DTc, ITCc, 288);
    k_reduce<<<768, 256, 0, stream>>>(Cpart, tok, tok_b, emb, 192 * DTc, DTc, 20, 2);

    // transformer block (all split-K GEMMs: partial-store + fused reduce, no atomics)
    k_layernorm<<<192, 256, 0, stream>>>(tok, ln1_g, ln1_b, ybuf);
    gemm_nt_p<<<dim3(48, 3, 8), 256, 0, stream>>>(ybuf, qkv_w, Cpart, 192, 3 * INNERc, DTc, 128);
    k_reduce<<<2304, 256, 0, stream>>>(Cpart, qkvB, nullptr, nullptr, 192 * 3 * INNERc,
                                       3 * INNERc, 8, 0);
    k_attention<<<12, 256, 0, stream>>>(qkvB, existB, obuf);
    gemm_nt_p<<<dim3(16, 3, 8), 256, 0, stream>>>(obuf, out_w, Cpart, 192, DTc, INNERc, 128);
    k_reduce<<<768, 256, 0, stream>>>(Cpart, tok, out_b, nullptr, 192 * DTc, DTc, 8, 1);
    k_layernorm<<<192, 256, 0, stream>>>(tok, ln2_g, ln2_b, ybuf);
    gemm_nt_p<<<dim3(32, 3, 8), 256, 0, stream>>>(ybuf, ff_w1, Cpart, 192, MLPc, DTc, 128);
    k_reduce<<<1536, 256, 0, stream>>>(Cpart, ffh, ff_b1, nullptr, 192 * MLPc, MLPc, 8, 3);
    gemm_nt_p<<<dim3(16, 3, 16), 256, 0, stream>>>(ffh, ff_w2, Cpart, 192, DTc, MLPc, 128);
    k_reduce<<<768, 256, 0, stream>>>(Cpart, tok, ff_b2, nullptr, 192 * DTc, DTc, 16, 1);
    k_layernorm<<<192, 256, 0, stream>>>(tok, lnf_g, lnf_b, ybuf);
    // dec: full-K plain-store with fused bias
    gemm_nt_f<<<dim3(90, 3), 256, 0, stream>>>(ybuf, dec_w, dec, dec_b, 192, ITCc, DTc);

    // scatter into x2 (copy of x); x2 aliases hbuf (Cpart dead after ff2 reduce)
    k_copy4<<<5184, 256, 0, stream>>>((const float4*)x, (float4*)x2, 1327104);
    k_scatter<<<144, 256, 0, stream>>>(dec, corrB, existB, x2);

    // ======== stage 2 ======== (dec consumed; Bpl overwrite is safe)
    k_split_x<<<20736, 256, 0, stream>>>(x2, Bpl, strideB);
    run_stage(17, 25, outExt2, outCls2, false);

    (void)in_sizes; (void)n_in; (void)out_size; (void)ws_size;
}

// Round 11
// 893.831 us; speedup vs baseline: 1.1988x; 1.0182x over previous
//
#include <hip/hip_runtime.h>
#include <math.h>

// ---- problem constants ----
#define Bb 32
#define DFc 8
#define Hh 144
#define Ww 144
#define OFFc 2
#define KWc 5
#define DSc 512
#define DTc 1024
#define NCc 6
#define HEADSc 16
#define DHc 64
#define MLPc 2048
#define CINc (DFc * Ww)        // 1152
#define ITCc (DFc * Hh * KWc)  // 5760
#define BHc (Bb * Hh)          // 4608
#define INNERc (HEADSc * DHc)  // 1024
#define EPSc 1e-5f
#define THRc 0.3f
#define WLNc 4608              // per-nc worklist capacity (max columns per nc)
#define GAPDELTA 1e-3f

typedef __attribute__((ext_vector_type(8))) short short8;
typedef __attribute__((ext_vector_type(4))) float f32x4;

// bf16 split helpers (manual RTN-even)
__device__ inline unsigned short f2bf(float v) {
    unsigned int u = __float_as_uint(v);
    unsigned int r = (u + 0x7FFFu + ((u >> 16) & 1u)) >> 16;
    return (unsigned short)r;
}
__device__ inline float bf2f(unsigned short b) {
    return __uint_as_float(((unsigned int)b) << 16);
}

// ============================================================
// Permute x(B,DF,H,W) -> Bt[n=(b*H+h)][k=(f*W+w)] and split into 2 bf16 planes.
// 2 elems/thread (pairs never straddle a W-row: Ww even, CINc even).
// ============================================================
__global__ void k_split_x(const float* __restrict__ x, unsigned short* __restrict__ p,
                          long planeStride)
{
    int t2 = blockIdx.x * 256 + threadIdx.x;  // pair index
    if (t2 >= BHc * CINc / 2) return;
    int tid = t2 * 2;
    int n = tid / CINc, k = tid % CINc;
    int b = n / Hh, h = n % Hh;
    int f = k / Ww, w = k % Ww;
    const float* xp = x + ((long)(b * DFc + f) * Hh + h) * Ww + w;
    float2 v = *(const float2*)xp;
    unsigned short h0 = f2bf(v.x), h1 = f2bf(v.y);
    ushort2 hi; hi.x = h0; hi.y = h1;
    ushort2 lo; lo.x = f2bf(v.x - bf2f(h0)); lo.y = f2bf(v.y - bf2f(h1));
    *(ushort2*)(p + tid) = hi;
    *(ushort2*)(p + planeStride + tid) = lo;
}

// ============================================================
// Tiled transpose: src [nc][512][1152] -> dst [nc][1152][512]
// grid (36, 16, 6), 256 threads (32x8)
// ============================================================
__global__ __launch_bounds__(256) void k_transpose(
    const float* __restrict__ src, float* __restrict__ dst)
{
    __shared__ float t[32][33];
    const int nc = blockIdx.z;
    const int s0 = blockIdx.y * 32;
    const int k0 = blockIdx.x * 32;
    const int lx = threadIdx.x & 31, ly = threadIdx.x >> 5;
    const float* sp = src + ((long)nc * 512 + s0) * 1152 + k0;
#pragma unroll
    for (int i = 0; i < 32; i += 8)
        t[ly + i][lx] = sp[(long)(ly + i) * 1152 + lx];
    __syncthreads();
    float* dp = dst + ((long)nc * 1152 + k0) * 512 + s0;
#pragma unroll
    for (int i = 0; i < 32; i += 8)
        dp[(long)(ly + i) * 512 + lx] = t[lx][ly + i];
}

// ============================================================
// W2s[nc][Mpad][512] = (o < O) ? w2[nc][o][s] * scale[nc*512+s] : 0
// ============================================================
__global__ void k_w2s(const float* __restrict__ w2, const float* __restrict__ scale,
                      float* __restrict__ Ws, int O, int Mpad)
{
    int i = blockIdx.x * 256 + threadIdx.x;
    if (i >= NCc * Mpad * 512) return;
    int s = i & 511;
    int o = (i >> 9) % Mpad;
    int nc = i / (Mpad * 512);
    float v = 0.f;
    if (o < O) v = w2[((long)nc * O + o) * 512 + s] * scale[nc * 512 + s];
    Ws[i] = v;
}

// ============================================================
// Batched plain-store NT GEMM: C[z][m][1152-ld] = A[z][m][K] @ B[z][n][K]^T
// 64x64 tile, BK=16, grid (n/64, m/64, z). Reg-prefetch pipelined.
// ============================================================
__global__ __launch_bounds__(256) void gemm_nt_b(
    const float* __restrict__ A, long sAz,
    const float* __restrict__ Bm, long sBz,
    float* __restrict__ C, long sCz, int K)
{
    __shared__ float As[16][68];
    __shared__ float Bs[16][68];
    const int tid = threadIdx.x;
    const int n0 = blockIdx.x * 64;
    const int m0 = blockIdx.y * 64;
    const int z = blockIdx.z;
    const int lRow = tid >> 2, lCol = (tid & 3) << 2;
    const int ty = tid >> 4, tx = tid & 15;
    const float* Az = A + (long)z * sAz + (long)(m0 + lRow) * K + lCol;
    const float* Bz = Bm + (long)z * sBz + (long)(n0 + lRow) * K + lCol;

    float acc[4][4];
#pragma unroll
    for (int i = 0; i < 4; i++)
#pragma unroll
        for (int j = 0; j < 4; j++) acc[i][j] = 0.f;

    float4 av = *(const float4*)(Az);
    float4 bv = *(const float4*)(Bz);
    for (int k0 = 0; k0 < K; k0 += 16) {
        As[lCol + 0][lRow] = av.x; As[lCol + 1][lRow] = av.y;
        As[lCol + 2][lRow] = av.z; As[lCol + 3][lRow] = av.w;
        Bs[lCol + 0][lRow] = bv.x; Bs[lCol + 1][lRow] = bv.y;
        Bs[lCol + 2][lRow] = bv.z; Bs[lCol + 3][lRow] = bv.w;
        __syncthreads();
        if (k0 + 16 < K) {
            av = *(const float4*)(Az + k0 + 16);
            bv = *(const float4*)(Bz + k0 + 16);
        }
#pragma unroll
        for (int kk = 0; kk < 16; kk++) {
            float4 a = *(const float4*)&As[kk][ty * 4];
            float4 b = *(const float4*)&Bs[kk][tx * 4];
            float aa[4] = {a.x, a.y, a.z, a.w};
            float bb[4] = {b.x, b.y, b.z, b.w};
#pragma unroll
            for (int i = 0; i < 4; i++)
#pragma unroll
                for (int j = 0; j < 4; j++) acc[i][j] += aa[i] * bb[j];
        }
        __syncthreads();
    }
    const int ncol = n0 + tx * 4;
#pragma unroll
    for (int i = 0; i < 4; i++) {
        float* cp = C + (long)z * sCz + (long)(m0 + ty * 4 + i) * 1152 + ncol;
#pragma unroll
        for (int j = 0; j < 4; j++) cp[j] = acc[i][j];
    }
}

// ============================================================
// effB[nc][256]: o<144: b2c + sum_s w2c[o][s]*shiftC; o in {144,145}:
// b2e + sum_s w2e[o-144][s]*shiftE; else 0. 16-lane group per output.
// ============================================================
__global__ __launch_bounds__(256) void k_effb(
    const float* __restrict__ w2c, const float* __restrict__ b2c, const float* __restrict__ shiftC,
    const float* __restrict__ w2e, const float* __restrict__ b2e, const float* __restrict__ shiftE,
    float* __restrict__ effB)
{
    int g = blockIdx.x * 16 + (threadIdx.x >> 4);
    int lane = threadIdx.x & 15;
    if (g >= NCc * 256) return;
    int nc = g >> 8, o = g & 255;
    float d = 0.f;
    if (o < 144) {
        const float* wp = w2c + ((long)nc * 144 + o) * 512;
        const float* sp = shiftC + nc * 512;
        for (int s = lane; s < 512; s += 16) d += wp[s] * sp[s];
    } else if (o < 146) {
        const float* wp = w2e + ((long)nc * 2 + (o - 144)) * 512;
        const float* sp = shiftE + nc * 512;
        for (int s = lane; s < 512; s += 16) d += wp[s] * sp[s];
    }
#pragma unroll
    for (int off = 8; off; off >>= 1) d += __shfl_xor(d, off);
    if (lane == 0) {
        float b = (o < 144) ? b2c[nc * 144 + o] : ((o < 146) ? b2e[nc * 2 + o - 144] : 0.f);
        effB[g] = d + b;
    }
}

// ============================================================
// Split effW fp32 [nc][256][1152] (rows >=208 garbage) into 2 bf16 planes
// ============================================================
__global__ void k_split_effw(const float* __restrict__ effW, unsigned short* __restrict__ p,
                             long planeStride)
{
    int i = blockIdx.x * 256 + threadIdx.x;  // over 6*256*1152 = 1,769,472
    if (i >= NCc * 256 * 1152) return;
    int o = (i / 1152) & 255;
    float v = (o < 208) ? effW[i] : 0.f;
    unsigned short h0 = f2bf(v);
    p[i] = h0;
    p[planeStride + i] = f2bf(v - bf2f(h0));
}

// ============================================================
// Fused head GEMM (MFMA, split-bf16, 3 products): per nc,
// logits[o][col] = effW[nc][o][:] . X[col][:]  (K=1152)
// grid (36, 2, 6), 128x128 tiles, BK=32, 2-phase dbuf + T2 both-sides swizzle.
// Epilogue: o<144 -> cls lgT[nc][col][o]; o==144 -> ext logits extLg[nc][col][2].
// ============================================================
__global__ __launch_bounds__(256) void gemm_fused(
    const unsigned short* __restrict__ Ag, long strideA,
    const unsigned short* __restrict__ Bg, long strideB,
    float* __restrict__ lgT, float* __restrict__ extLg,
    const float* __restrict__ effB)
{
    constexpr int K = 1152;
    constexpr int PAt[3] = {0, 0, 1};
    constexpr int PBt[3] = {0, 1, 0};
    __shared__ __align__(16) unsigned short As[2][2][128 * 32];
    __shared__ __align__(16) unsigned short Bs[2][2][128 * 32];
    const int tid = threadIdx.x;
    const int w = tid >> 6;
    const int l = tid & 63;
    const int quad = l >> 4, l15 = l & 15;
    const int z = blockIdx.z;
    const int m0 = blockIdx.y * 128, n0 = blockIdx.x * 128;
    const int rw = (w >> 1) * 64, cw = (w & 1) * 64;

    f32x4 acc[4][4];
#pragma unroll
    for (int i = 0; i < 4; i++)
#pragma unroll
        for (int j = 0; j < 4; j++) acc[i][j] = (f32x4){0.f, 0.f, 0.f, 0.f};

    const int srow = w * 32;
    const int lr = l >> 2;
    const int lc = ((l & 3) ^ ((lr >> 1) & 3)) * 8;  // pre-swizzled source slot
    const unsigned short* gA[2];
    const unsigned short* gB[2];
#pragma unroll
    for (int p = 0; p < 2; p++) {
        gA[p] = Ag + (long)p * strideA + ((long)(z * 256 + m0 + srow + lr)) * K + lc;
        gB[p] = Bg + (long)p * strideB + ((long)(n0 + srow + lr)) * K + lc;
    }
    const int ldsOff0 = srow * 32;
    const int ldsOff1 = (srow + 16) * 32;
    const int rdoff = (quad ^ ((l15 >> 1) & 3)) * 8;  // swizzled read slot

    auto STAGE = [&](int buf, int k0) {
#pragma unroll
        for (int p = 0; p < 2; p++) {
            __builtin_amdgcn_global_load_lds(
                (const __attribute__((address_space(1))) void*)(gA[p] + k0),
                (__attribute__((address_space(3))) void*)&As[buf][p][ldsOff0], 16, 0, 0);
            __builtin_amdgcn_global_load_lds(
                (const __attribute__((address_space(1))) void*)(gA[p] + 16 * K + k0),
                (__attribute__((address_space(3))) void*)&As[buf][p][ldsOff1], 16, 0, 0);
            __builtin_amdgcn_global_load_lds(
                (const __attribute__((address_space(1))) void*)(gB[p] + k0),
                (__attribute__((address_space(3))) void*)&Bs[buf][p][ldsOff0], 16, 0, 0);
            __builtin_amdgcn_global_load_lds(
                (const __attribute__((address_space(1))) void*)(gB[p] + 16 * K + k0),
                (__attribute__((address_space(3))) void*)&Bs[buf][p][ldsOff1], 16, 0, 0);
        }
    };

    const int nk = K >> 5;  // 36
    STAGE(0, 0);
    __syncthreads();
    int cur = 0;
    for (int t = 0; t < nk; ++t) {
        if (t + 1 < nk) STAGE(cur ^ 1, (t + 1) << 5);

        short8 af[2][4], bf[2][4];
#pragma unroll
        for (int p = 0; p < 2; p++)
#pragma unroll
            for (int i = 0; i < 4; i++) {
                af[p][i] = *(const short8*)&As[cur][p][(rw + i * 16 + l15) * 32 + rdoff];
                bf[p][i] = *(const short8*)&Bs[cur][p][(cw + i * 16 + l15) * 32 + rdoff];
            }
#pragma unroll
        for (int t2 = 0; t2 < 3; t2++) {
            const int pa = PAt[t2], pb = PBt[t2];
#pragma unroll
            for (int i = 0; i < 4; i++)
#pragma unroll
                for (int j = 0; j < 4; j++)
                    acc[i][j] = __builtin_amdgcn_mfma_f32_16x16x32_bf16(
                        af[pa][i], bf[pb][j], acc[i][j], 0, 0, 0);
        }
        __syncthreads();
        cur ^= 1;
    }

#pragma unroll
    for (int i = 0; i < 4; i++) {
        int ob = m0 + rw + i * 16 + quad * 4;
        if (ob < 144) {
            float4 bb = *(const float4*)(effB + z * 256 + ob);
#pragma unroll
            for (int j = 0; j < 4; j++) {
                int col = n0 + cw + j * 16 + l15;
                float4 v = make_float4(acc[i][j][0] + bb.x, acc[i][j][1] + bb.y,
                                       acc[i][j][2] + bb.z, acc[i][j][3] + bb.w);
                *(float4*)(lgT + ((long)(z * BHc + col)) * 144 + ob) = v;
            }
        } else if (ob == 144) {
            float b0 = effB[z * 256 + 144];
            float b1 = effB[z * 256 + 145];
#pragma unroll
            for (int j = 0; j < 4; j++) {
                int col = n0 + cw + j * 16 + l15;
                float* ep = extLg + ((long)z * BHc + col) * 2;
                ep[0] = acc[i][j][0] + b0;
                ep[1] = acc[i][j][1] + b1;
            }
        }
    }
}

// ============================================================
// Split-K NT GEMM, PARTIAL-STORE (no atomics): Cpart[z][m][n] = partial sum
// over k-chunk z. 64x64 tile, BK=16, reg-prefetch pipelined.
// kc MUST be a multiple of 16.
// ============================================================
__global__ __launch_bounds__(256) void gemm_nt_p(
    const float* __restrict__ A, const float* __restrict__ Bm, float* __restrict__ Cpart,
    int M, int N, int K, int kc)
{
    __shared__ float As[16][68];
    __shared__ float Bs[16][68];
    const int tid = threadIdx.x;
    const int n0 = blockIdx.x * 64;
    const int m0 = blockIdx.y * 64;
    const int ks = blockIdx.z * kc;
    const int ke = min(K, ks + kc);
    const int lRow = tid >> 2, lCol = (tid & 3) << 2;
    const int ty = tid >> 4, tx = tid & 15;
    const float* Ap = A + (long)(m0 + lRow) * K + lCol;
    const float* Bp = Bm + (long)(n0 + lRow) * K + lCol;

    float acc[4][4];
#pragma unroll
    for (int i = 0; i < 4; i++)
#pragma unroll
        for (int j = 0; j < 4; j++) acc[i][j] = 0.f;

    float4 av = *(const float4*)(Ap + ks);
    float4 bv = *(const float4*)(Bp + ks);
    for (int k0 = ks; k0 < ke; k0 += 16) {
        As[lCol + 0][lRow] = av.x; As[lCol + 1][lRow] = av.y;
        As[lCol + 2][lRow] = av.z; As[lCol + 3][lRow] = av.w;
        Bs[lCol + 0][lRow] = bv.x; Bs[lCol + 1][lRow] = bv.y;
        Bs[lCol + 2][lRow] = bv.z; Bs[lCol + 3][lRow] = bv.w;
        __syncthreads();
        if (k0 + 16 < ke) {
            av = *(const float4*)(Ap + k0 + 16);
            bv = *(const float4*)(Bp + k0 + 16);
        }
#pragma unroll
        for (int kk = 0; kk < 16; kk++) {
            float4 a = *(const float4*)&As[kk][ty * 4];
            float4 b = *(const float4*)&Bs[kk][tx * 4];
            float aa[4] = {a.x, a.y, a.z, a.w};
            float bb[4] = {b.x, b.y, b.z, b.w};
#pragma unroll
            for (int i = 0; i < 4; i++)
#pragma unroll
                for (int j = 0; j < 4; j++) acc[i][j] += aa[i] * bb[j];
        }
        __syncthreads();
    }
    const int ncol = n0 + tx * 4;
    float* base = Cpart + (long)blockIdx.z * M * N;
#pragma unroll
    for (int i = 0; i < 4; i++) {
        float* cp = base + (long)(m0 + ty * 4 + i) * N + ncol;
        cp[0] = acc[i][0];
        cp[1] = acc[i][1];
        cp[2] = acc[i][2];
        cp[3] = acc[i][3];
    }
}

// ============================================================
// Reduce partials + fused epilogue.
// mode 0: C = bias + sum            (bias may be null -> 0)
// mode 1: C += bias + sum           (residual add)
// mode 2: C = bias + emb[(row%NC)*N+n] + sum   (tok init fused)
// mode 3: C = gelu(bias + sum)      (ff1 + gelu fused)
// ============================================================
__global__ void k_reduce(const float* __restrict__ Cpart, float* __restrict__ C,
                         const float* __restrict__ bias, const float* __restrict__ emb,
                         int MN, int N, int Z, int mode)
{
    int idx = blockIdx.x * 256 + threadIdx.x;
    if (idx >= MN) return;
    int n = idx % N;
    float s = 0.f;
    for (int z = 0; z < Z; z++) s += Cpart[(long)z * MN + idx];
    float b = bias ? bias[n] : 0.f;
    if (mode == 2) { int row = idx / N; b += emb[(row % NCc) * N + n]; }
    float v = s + b;
    if (mode == 3) v = 0.5f * v * (1.f + erff(v * 0.70710678118654752440f));
    if (mode == 1) C[idx] += v;
    else C[idx] = v;
}

// scale = g*rsqrt(vr+eps); shift = (b1-mu)*scale + bt; optionally zero worklist cnts
__global__ void k_scale_shift(const float* __restrict__ g, const float* __restrict__ vr,
                              const float* __restrict__ mu, const float* __restrict__ bt,
                              const float* __restrict__ b1,
                              float* __restrict__ scale, float* __restrict__ shift, int n,
                              int* __restrict__ wlc)
{
    int i = blockIdx.x * 256 + threadIdx.x;
    if (wlc && i < 8) wlc[i] = 0;
    if (i >= n) return;
    float sc = g[i] * rsqrtf(vr[i] + EPSc);
    scale[i] = sc;
    shift[i] = (b1[i] - mu[i]) * sc + bt[i];
}

// ext head from precomputed logits: softmax (O=2) + exist reduction
__global__ __launch_bounds__(256) void k_ext_head2(
    const float* __restrict__ extLg, float* __restrict__ outExt, int* __restrict__ exist)
{
    __shared__ float red[256];
    const int bc = blockIdx.x;
    const int b = bc / NCc, nc = bc % NCc;
    const int h = threadIdx.x;
    float p0 = 0.f;
    if (h < Hh) {
        const int col = b * Hh + h;
        const float* ep = extLg + ((long)nc * BHc + col) * 2;
        float lg0 = ep[0], lg1 = ep[1];
        float mx = fmaxf(lg0, lg1);
        float e0 = expf(lg0 - mx), e1 = expf(lg1 - mx);
        float inv = 1.f / (e0 + e1);
        p0 = e0 * inv;
        float* op = outExt + ((long)bc * Hh + h) * 2;
        op[0] = p0;
        op[1] = e1 * inv;
    }
    red[threadIdx.x] = p0;
    __syncthreads();
    for (int st = 128; st > 0; st >>= 1) {
        if (threadIdx.x < st) red[threadIdx.x] += red[threadIdx.x + st];
        __syncthreads();
    }
    if (threadIdx.x == 0) exist[bc] = (red[0] / Hh > THRc) ? 1 : 0;
}

// ============================================================
// wave-per-column softmax over lgT[nc][col][144]; top-2 gap flagging (stage1),
// bucketed per-nc worklist: wlc[nc] count, wl[nc*WLN + ix] = col.
// ============================================================
__global__ __launch_bounds__(256) void k_softmax2(
    const float* __restrict__ lgT, float* __restrict__ outCls, int* __restrict__ corr,
    int* __restrict__ wlc, int* __restrict__ wl, int stage1)
{
    int wg = blockIdx.x * 4 + (threadIdx.x >> 6);
    int l = threadIdx.x & 63;
    int nc = wg / BHc, col = wg % BHc;
    int b = col / Hh, h = col % Hh;
    const float* p = lgT + ((long)nc * BHc + col) * 144;
    float v0 = p[l];
    float v1 = p[l + 64];
    float v2 = (l < 16) ? p[l + 128] : -1e30f;
    // per-lane top2 (lower idx wins ties)
    float m1 = v0, m2; int i1 = l;
    if (v1 > m1) { m2 = m1; m1 = v1; i1 = l + 64; } else m2 = v1;
    if (v2 > m1) { m2 = m1; m1 = v2; i1 = l + 128; } else m2 = fmaxf(m2, v2);
    // butterfly top2 merge across 64 lanes
#pragma unroll
    for (int off = 32; off; off >>= 1) {
        float o1 = __shfl_xor(m1, off);
        float o2 = __shfl_xor(m2, off);
        int oi = __shfl_xor(i1, off);
        if (o1 > m1 || (o1 == m1 && oi < i1)) { m2 = fmaxf(m1, o2); m1 = o1; i1 = oi; }
        else m2 = fmaxf(m2, o1);
    }
    float e0 = expf(v0 - m1);
    float e1 = expf(v1 - m1);
    float e2 = (l < 16) ? expf(v2 - m1) : 0.f;
    float s = e0 + e1 + e2;
#pragma unroll
    for (int off = 32; off; off >>= 1) s += __shfl_xor(s, off);
    float inv = 1.f / s;
    int row = (b * NCc + nc) * Hh + h;
    float* op = outCls + (long)row * 144;
    op[l] = e0 * inv;
    op[l + 64] = e1 * inv;
    if (l < 16) op[l + 128] = e2 * inv;
    if (l == 0) {
        corr[row] = i1;
        if (stage1 && (m1 - m2) < GAPDELTA) {
            int ix = atomicAdd(&wlc[nc], 1);
            if (ix < WLNc) wl[nc * WLNc + ix] = col;
        }
    }
}

// ============================================================
// fixup phase A: exact fp32 h for flagged items.
// ============================================================
__global__ __launch_bounds__(256) void k_fixup_h(
    const float* __restrict__ x, const float* __restrict__ w1,
    const float* __restrict__ scale, const float* __restrict__ shift,
    const int* __restrict__ wlc, const int* __restrict__ wl,
    float* __restrict__ hsfix)
{
    const int nc = blockIdx.y;
    const int cnt = min(wlc[nc], WLNc);
    const int chunk = blockIdx.z;  // 0..7
    if (chunk >= cnt) return;
    const int t = threadIdx.x;
    const int r = t >> 4;          // 0..15
    const int lane16 = t & 15;
    const int s = blockIdx.x * 16 + r;  // 0..511
    const float* wp = w1 + ((long)(nc * 512 + s)) * CINc + lane16 * 4;
    float4 wr[18];
#pragma unroll
    for (int i = 0; i < 18; i++) wr[i] = *(const float4*)(wp + 64 * i);
    const float sc = scale[nc * 512 + s];
    const float sh = shift[nc * 512 + s];
    int xoff[18];
#pragma unroll
    for (int i = 0; i < 18; i++) {
        int k = lane16 * 4 + 64 * i;
        xoff[i] = (k / Ww) * (Hh * Ww) + (k % Ww);
    }
    for (int it = chunk; it < cnt; it += 8) {
        int col = wl[nc * WLNc + it];
        int b = col / Hh, h = col % Hh;
        const float* xb = x + (long)b * (DFc * Hh * Ww) + h * Ww;
        float d = 0.f;
#pragma unroll
        for (int i = 0; i < 18; i++) {
            float4 xv = *(const float4*)(xb + xoff[i]);
            d += wr[i].x * xv.x + wr[i].y * xv.y + wr[i].z * xv.z + wr[i].w * xv.w;
        }
#pragma unroll
        for (int off = 8; off; off >>= 1) d += __shfl_xor(d, off);
        if (lane16 == 0) hsfix[((long)nc * WLNc + it) * 512 + s] = d * sc + sh;
    }
}

// ============================================================
// fixup phase B: exact logits lgfix[nc][item][144] = w2 @ hsfix + b2.
// ============================================================
__global__ __launch_bounds__(256) void k_fixup_lg(
    const float* __restrict__ hsfix, const float* __restrict__ w2,
    const float* __restrict__ b2,
    const int* __restrict__ wlc, const int* __restrict__ wl,
    float* __restrict__ lgfix)
{
    const int nc = blockIdx.y;
    const int cnt = min(wlc[nc], WLNc);
    const int chunk = blockIdx.z;
    if (chunk >= cnt) return;
    const int t = threadIdx.x;
    const int r = t >> 4;
    const int lane16 = t & 15;
    const int o = blockIdx.x * 16 + r;  // 0..143
    const float* wp = w2 + ((long)(nc * 144 + o)) * 512 + lane16 * 4;
    float4 wr[8];
#pragma unroll
    for (int i = 0; i < 8; i++) wr[i] = *(const float4*)(wp + 64 * i);
    const float bb = b2[nc * 144 + o];
    for (int it = chunk; it < cnt; it += 8) {
        const float* hp = hsfix + ((long)nc * WLNc + it) * 512 + lane16 * 4;
        float d = 0.f;
#pragma unroll
        for (int i = 0; i < 8; i++) {
            float4 hv = *(const float4*)(hp + 64 * i);
            d += wr[i].x * hv.x + wr[i].y * hv.y + wr[i].z * hv.z + wr[i].w * hv.w;
        }
#pragma unroll
        for (int off = 8; off; off >>= 1) d += __shfl_xor(d, off);
        if (lane16 == 0) lgfix[((long)nc * WLNc + it) * 144 + o] = d + bb;
    }
}

// ============================================================
// fixup phase C: per flagged item (one wave each): exact argmax (lower-idx
// tie, matches jnp.argmax) + exact softmax -> outCls, corr.
// ============================================================
__global__ __launch_bounds__(256) void k_fixup_fin(
    const float* __restrict__ lgfix,
    const int* __restrict__ wlc, const int* __restrict__ wl,
    float* __restrict__ outCls, int* __restrict__ corr)
{
    int c[6];
    int total = 0;
#pragma unroll
    for (int i = 0; i < 6; i++) { c[i] = min(wlc[i], WLNc); total += c[i]; }
    const int wid = threadIdx.x >> 6;
    const int l = threadIdx.x & 63;
    for (int g = blockIdx.x * 4 + wid; g < total; g += gridDim.x * 4) {
        int nc = 0, base = 0;
        while (nc < 5 && g >= base + c[nc]) { base += c[nc]; nc++; }
        int it = g - base;
        int col = wl[nc * WLNc + it];
        int b = col / Hh, h = col % Hh;
        const float* p = lgfix + ((long)nc * WLNc + it) * 144;
        float v0 = p[l];
        float v1 = p[l + 64];
        float v2 = (l < 16) ? p[l + 128] : -1e30f;
        float m1 = v0; int i1 = l;
        if (v1 > m1) { m1 = v1; i1 = l + 64; }
        if (v2 > m1) { m1 = v2; i1 = l + 128; }
#pragma unroll
        for (int off = 32; off; off >>= 1) {
            float o1 = __shfl_xor(m1, off);
            int oi = __shfl_xor(i1, off);
            if (o1 > m1 || (o1 == m1 && oi < i1)) { m1 = o1; i1 = oi; }
        }
        float e0 = expf(v0 - m1);
        float e1 = expf(v1 - m1);
        float e2 = (l < 16) ? expf(v2 - m1) : 0.f;
        float s = e0 + e1 + e2;
#pragma unroll
        for (int off = 32; off; off >>= 1) s += __shfl_xor(s, off);
        float inv = 1.f / s;
        int row = (b * NCc + nc) * Hh + h;
        float* op = outCls + (long)row * 144;
        op[l] = e0 * inv;
        op[l + 64] = e1 * inv;
        if (l < 16) op[l + 128] = e2 * inv;
        if (l == 0) corr[row] = i1;
    }
}

// gather window: win[(b*NC+nc)][f*H*K + h*K + k]
__global__ void k_gather(const float* __restrict__ x, const int* __restrict__ corr,
                         float* __restrict__ win)
{
    int tid = blockIdx.x * 256 + threadIdx.x;
    if (tid >= Bb * NCc * ITCc) return;
    int row = tid / ITCc, i = tid % ITCc;
    int b = row / NCc, nc = row % NCc;
    int f = i / (Hh * KWc);
    int r = i % (Hh * KWc);
    int h = r / KWc, k = r % KWc;
    int j = corr[(b * NCc + nc) * Hh + h] + k - OFFc;
    float v = 0.f;
    if (j >= 0 && j < Ww) v = x[((long)(b * DFc + f) * Hh + h) * Ww + j];
    win[tid] = v;
}

__global__ __launch_bounds__(256) void k_layernorm(
    const float* __restrict__ in, const float* __restrict__ g,
    const float* __restrict__ bta, float* __restrict__ out)
{
    __shared__ float r1[256], r2[256];
    const int row = blockIdx.x;
    const int t = threadIdx.x;
    const float* p = in + (long)row * DTc;
    float s = 0.f, sq = 0.f;
    for (int i = t; i < DTc; i += 256) {
        float v = p[i];
        s += v; sq += v * v;
    }
    r1[t] = s; r2[t] = sq;
    __syncthreads();
    for (int st = 128; st > 0; st >>= 1) {
        if (t < st) { r1[t] += r1[t + st]; r2[t] += r2[t + st]; }
        __syncthreads();
    }
    float mean = r1[0] / DTc;
    float var = r2[0] / DTc - mean * mean;
    float rstd = rsqrtf(var + EPSc);
    float* o = out + (long)row * DTc;
    for (int i = t; i < DTc; i += 256) o[i] = (p[i] - mean) * rstd * g[i] + bta[i];
}

// tiny attention: one thread per (b, head, n)
__global__ void k_attention(const float* __restrict__ qkv, const int* __restrict__ exist,
                            float* __restrict__ obuf)
{
    int idx = blockIdx.x * 256 + threadIdx.x;
    if (idx >= Bb * HEADSc * NCc) return;
    int b = idx / (HEADSc * NCc);
    int r = idx % (HEADSc * NCc);
    int hd = r / NCc, n = r % NCc;
    const float* base = qkv + (long)b * NCc * (3 * INNERc);
    const float* q = base + (long)n * (3 * INNERc) + hd * DHc;
    float s[NCc];
    for (int m = 0; m < NCc; m++) {
        const float* kp = base + (long)m * (3 * INNERc) + INNERc + hd * DHc;
        float d = 0.f;
        for (int t = 0; t < DHc; t++) d += q[t] * kp[t];
        s[m] = exist[b * NCc + m] ? d * 0.125f : -1e9f;
    }
    float mx = s[0];
    for (int m = 1; m < NCc; m++) mx = fmaxf(mx, s[m]);
    float sum = 0.f;
    for (int m = 0; m < NCc; m++) { s[m] = expf(s[m] - mx); sum += s[m]; }
    float inv = 1.f / sum;
    for (int m = 0; m < NCc; m++) s[m] *= inv;
    float* op = obuf + (long)(b * NCc + n) * INNERc + hd * DHc;
    for (int t = 0; t < DHc; t++) {
        float acc = 0.f;
        for (int m = 0; m < NCc; m++)
            acc += s[m] * base[(long)m * (3 * INNERc) + 2 * INNERc + hd * DHc + t];
        op[t] = acc;
    }
}

__global__ void k_copy4(const float4* __restrict__ s, float4* __restrict__ d, int n)
{
    int tid = blockIdx.x * 256 + threadIdx.x;
    if (tid < n) d[tid] = s[tid];
}

// scatter dec into x2; per-(b,h,f) thread, c descending, first-writer-wins per column
__global__ void k_scatter(const float* __restrict__ dec, const int* __restrict__ corr,
                          const int* __restrict__ exist, float* __restrict__ x2)
{
    int idx = blockIdx.x * 256 + threadIdx.x;
    if (idx >= Bb * Hh * DFc) return;
    int b = idx / (Hh * DFc);
    int r = idx % (Hh * DFc);
    int h = r / DFc, f = r % DFc;
    if (h >= Hh - 1) return;  // hmask
    unsigned long long m0 = 0ull, m1 = 0ull, m2 = 0ull;
    float* xrow = x2 + ((long)(b * DFc + f) * Hh + h) * Ww;
    for (int c = NCc - 1; c >= 0; c--) {
        if (!exist[b * NCc + c]) continue;
        int cr = corr[(b * NCc + c) * Hh + h];
        const float* dp = dec + (long)(b * NCc + c) * ITCc + f * (Hh * KWc) + h * KWc;
        for (int k = 0; k < KWc; k++) {
            int j = cr + k - OFFc;
            if (j < 0 || j >= Ww) continue;
            bool seen;
            if (j < 64) { unsigned long long bit = 1ull << j; seen = (m0 & bit) != 0; m0 |= bit; }
            else if (j < 128) { unsigned long long bit = 1ull << (j - 64); seen = (m1 & bit) != 0; m1 |= bit; }
            else { unsigned long long bit = 1ull << (j - 128); seen = (m2 & bit) != 0; m2 |= bit; }
            if (!seen) xrow[j] = dp[k];
        }
    }
}

extern "C" void kernel_launch(void* const* d_in, const int* in_sizes, int n_in,
                              void* d_out, int out_size, void* d_ws, size_t ws_size,
                              hipStream_t stream)
{
    const float* const* in = (const float* const*)d_in;
    const float* x = in[0];
    // input index bases: ext=1, cls=9, ext2=17, cls2=25
    const float* emb = in[33];
    const float* tok_w = in[34]; const float* tok_b = in[35];
    const float* ln1_g = in[36]; const float* ln1_b = in[37];
    const float* qkv_w = in[38];
    const float* out_w = in[39]; const float* out_b = in[40];
    const float* ln2_g = in[41]; const float* ln2_b = in[42];
    const float* ff_w1 = in[43]; const float* ff_b1 = in[44];
    const float* ff_w2 = in[45]; const float* ff_b2 = in[46];
    const float* lnf_g = in[47]; const float* lnf_b = in[48];
    const float* dec_w = in[49]; const float* dec_b = in[50];

    float* out = (float*)d_out;
    float* outExt1 = out;
    float* outCls1 = out + 55296;
    float* outExt2 = out + 4036608;
    float* outCls2 = out + 4091904;

    // ---- workspace layout (floats) ----
    const long strideB  = (long)BHc * CINc;         // 5,308,416 bf16 / plane (x)
    const long strideApl = (long)NCc * 256 * 1152;  // 1,769,472 bf16 / plane (effW)
    float* ws = (float*)d_ws;
    // hbuf region [0 .. 14,155,776):
    float* w1Tc  = ws;                 // 3,538,944 (cls w1^T)
    float* w1Te  = ws + 3538944;       // 3,538,944 (ext w1^T)
    float* effWf = ws + 7077888;       // 1,769,472 (effW fp32 [nc][256][1152])
    float* lgTn  = ws + 8847360;       // 3,981,312 (cls logits lgT[nc][col][144])
    float* hsfix = ws;                 // alias: fixup exact h (after lgT consumed)
    float* x2    = ws;                 // alias: stage-boundary x2 (first 5.3M)
    float* Cpart = ws;                 // alias: split-K partials (transformer; max 4.72M f)
    unsigned short* Apl = (unsigned short*)(ws + 14155776);   // 2 effW planes (3.54M shorts)
    // Apl2 region [17694720 .. 18481152):
    float* W2s    = ws + 17694720;            // <= 589,824 (w2*scale padded)
    float* extLg  = ws + 17694720;            // 55,296 (alias; after W2s dead)
    float* scaleE = ws + 17694720 + 589824;   // 3072
    float* shiftE = scaleE + 3072;            // 3072
    float* effB   = shiftE + 3072;            // 1536
    unsigned short* Bpl = (unsigned short*)(ws + 18481152);   // 2 planes x
    float* lgfix = ws + 18481152;             // fixup exact logits (Bpl alias, post-GEMM)
    float* windec = ws + 18481152;            // alias over Bpl
    float* tok  = windec + 1105920;
    float* ybuf = tok + 196608;
    float* qkvB = ybuf + 196608;
    float* obuf = qkvB + 589824;
    float* ffh  = obuf + 196608;
    float* scaleB = ws + 26443776;
    float* shiftB = scaleB + 3072;
    int* corrB  = (int*)(shiftB + 3072);                 // 27648
    int* existB = corrB + 27648;                         // 192
    int* wlcB   = existB + 192;                          // 8 (per-nc counts)
    int* wlB    = wlcB + 8;                              // 6*WLN = 27648
    float* win = windec;
    float* dec = windec;

    auto run_stage = [&](int be, int bc, float* oExt, float* oCls, bool stage1) {
        // scale/shift (cls kept for fixup), zero worklist counters
        k_scale_shift<<<12, 256, 0, stream>>>(in[bc + 2], in[bc + 5], in[bc + 4],
                                              in[bc + 3], in[bc + 1], scaleB, shiftB,
                                              NCc * DSc, wlcB);
        k_scale_shift<<<12, 256, 0, stream>>>(in[be + 2], in[be + 5], in[be + 4],
                                              in[be + 3], in[be + 1], scaleE, shiftE,
                                              NCc * DSc, nullptr);
        // w1 transposes -> [nc][1152][512]
        k_transpose<<<dim3(36, 16, 6), 256, 0, stream>>>(in[bc + 0], w1Tc);
        k_transpose<<<dim3(36, 16, 6), 256, 0, stream>>>(in[be + 0], w1Te);
        // effW = (w2*scale) @ w1  (fp32), cls rows 0..143 then ext rows 144..145
        k_w2s<<<2304, 256, 0, stream>>>(in[bc + 6], scaleB, W2s, 144, 192);
        gemm_nt_b<<<dim3(18, 3, 6), 256, 0, stream>>>(W2s, (long)192 * 512, w1Tc,
                                                      (long)1152 * 512, effWf,
                                                      (long)256 * 1152, 512);
        k_w2s<<<768, 256, 0, stream>>>(in[be + 6], scaleE, W2s, 2, 64);
        gemm_nt_b<<<dim3(18, 1, 6), 256, 0, stream>>>(W2s, (long)64 * 512, w1Te,
                                                      (long)1152 * 512,
                                                      effWf + (long)144 * 1152,
                                                      (long)256 * 1152, 512);
        // effB = b2 + w2 @ shift
        k_effb<<<96, 256, 0, stream>>>(in[bc + 6], in[bc + 7], shiftB,
                                       in[be + 6], in[be + 7], shiftE, effB);
        // split effW to bf16 planes, run fused head GEMM
        k_split_effw<<<6912, 256, 0, stream>>>(effWf, Apl, strideApl);
        gemm_fused<<<dim3(36, 2, 6), 256, 0, stream>>>(Apl, strideApl, Bpl, strideB,
                                                       lgTn, extLg, effB);
        // heads
        k_ext_head2<<<Bb * NCc, 256, 0, stream>>>(extLg, oExt, existB);
        k_softmax2<<<6912, 256, 0, stream>>>(lgTn, oCls, corrB, wlcB, wlB, stage1 ? 1 : 0);
        if (stage1) {
            // exact fp32 recompute (hsfix clobbers hbuf region; lgT already consumed)
            k_fixup_h<<<dim3(32, NCc, 8), 256, 0, stream>>>(x, in[bc + 0], scaleB, shiftB,
                                                            wlcB, wlB, hsfix);
            k_fixup_lg<<<dim3(9, NCc, 8), 256, 0, stream>>>(hsfix, in[bc + 6], in[bc + 7],
                                                            wlcB, wlB, lgfix);
            k_fixup_fin<<<512, 256, 0, stream>>>(lgfix, wlcB, wlB, oCls, corrB);
        }
    };

    // ======== stage 1 ========
    k_split_x<<<10368, 256, 0, stream>>>(x, Bpl, strideB);
    run_stage(1, 9, outExt1, outCls1, true);

    // gather + token projection (win clobbers lgfix/Bpl — both dead by now).
    // Cpart lives in the hbuf region (dead until k_copy4 writes x2 after dec).
    k_gather<<<4320, 256, 0, stream>>>(x, corrB, win);
    // tok: 20 chunks x kc=288 (mult of 16), partial-store + reduce (fuses tok_b+emb)
    gemm_nt_p<<<dim3(16, 3, 20), 256, 0, stream>>>(win, tok_w, Cpart, 192, DTc, ITCc, 288);
    k_reduce<<<768, 256, 0, stream>>>(Cpart, tok, tok_b, emb, 192 * DTc, DTc, 20, 2);

    // transformer block (all split-K GEMMs: partial-store + fused reduce, no atomics)
    k_layernorm<<<192, 256, 0, stream>>>(tok, ln1_g, ln1_b, ybuf);
    gemm_nt_p<<<dim3(48, 3, 8), 256, 0, stream>>>(ybuf, qkv_w, Cpart, 192, 3 * INNERc, DTc, 128);
    k_reduce<<<2304, 256, 0, stream>>>(Cpart, qkvB, nullptr, nullptr, 192 * 3 * INNERc,
                                       3 * INNERc, 8, 0);
    k_attention<<<12, 256, 0, stream>>>(qkvB, existB, obuf);
    gemm_nt_p<<<dim3(16, 3, 8), 256, 0, stream>>>(obuf, out_w, Cpart, 192, DTc, INNERc, 128);
    k_reduce<<<768, 256, 0, stream>>>(Cpart, tok, out_b, nullptr, 192 * DTc, DTc, 8, 1);
    k_layernorm<<<192, 256, 0, stream>>>(tok, ln2_g, ln2_b, ybuf);
    gemm_nt_p<<<dim3(32, 3, 8), 256, 0, stream>>>(ybuf, ff_w1, Cpart, 192, MLPc, DTc, 128);
    k_reduce<<<1536, 256, 0, stream>>>(Cpart, ffh, ff_b1, nullptr, 192 * MLPc, MLPc, 8, 3);
    gemm_nt_p<<<dim3(16, 3, 16), 256, 0, stream>>>(ffh, ff_w2, Cpart, 192, DTc, MLPc, 128);
    k_reduce<<<768, 256, 0, stream>>>(Cpart, tok, ff_b2, nullptr, 192 * DTc, DTc, 16, 1);
    k_layernorm<<<192, 256, 0, stream>>>(tok, lnf_g, lnf_b, ybuf);
    // dec: split-K 4 chunks (kc=256), partial-store + reduce with fused dec_b
    gemm_nt_p<<<dim3(90, 3, 4), 256, 0, stream>>>(ybuf, dec_w, Cpart, 192, ITCc, DTc, 256);
    k_reduce<<<4320, 256, 0, stream>>>(Cpart, dec, dec_b, nullptr, 192 * ITCc, ITCc, 4, 0);

    // scatter into x2 (copy of x); x2 aliases hbuf (Cpart dead after dec reduce)
    k_copy4<<<5184, 256, 0, stream>>>((const float4*)x, (float4*)x2, 1327104);
    k_scatter<<<144, 256, 0, stream>>>(dec, corrB, existB, x2);

    // ======== stage 2 ======== (dec consumed; Bpl overwrite is safe)
    k_split_x<<<10368, 256, 0, stream>>>(x2, Bpl, strideB);
    run_stage(17, 25, outExt2, outCls2, false);

    (void)in_sizes; (void)n_in; (void)out_size; (void)ws_size;
}